// Round 14
// baseline (633.236 us; speedup 1.0000x reference)
//
#include <hip/hip_runtime.h>
#include <math.h>

// OctreeAttention: C=256, H=8, HD=32, K=32, G=8, W=40, NW=4096, RPE rows=153
#define SCALE_F 0.17677669529663687f  // 32^-0.5

typedef __bf16 bf16x8 __attribute__((ext_vector_type(8)));
typedef float f32x4 __attribute__((ext_vector_type(4)));

__device__ __forceinline__ unsigned short f2bf(float f) {
  unsigned u = __builtin_bit_cast(unsigned, f);
  u = (u + 0x7FFFu + ((u >> 16) & 1u)) >> 16;
  return (unsigned short)u;
}
__device__ __forceinline__ float bf2f(unsigned short u) {
  return __builtin_bit_cast(float, (unsigned)u << 16);
}
__device__ __forceinline__ unsigned pk2(float a, float b) {
  return (unsigned)f2bf(a) | ((unsigned)f2bf(b) << 16);
}
__device__ __forceinline__ bf16x8 ld16(const void* p) {
  int4 v = *(const int4*)p;
  return __builtin_bit_cast(bf16x8, v);
}
__device__ __forceinline__ void gll16(const void* g, void* l) {
  __builtin_amdgcn_global_load_lds(
      (const __attribute__((address_space(1))) unsigned int*)g,
      (__attribute__((address_space(3))) unsigned int*)l, 16, 0, 0);
}

// =======================================================================
// TIER-1 PATH (ws >= 252 MB, proven on this harness)
// =======================================================================

// ---- prep: weights -> bf16, chunked pre-swizzled ----
__global__ void octa_prep2(const float* __restrict__ qkv_w, const float* __restrict__ proj_w,
                           unsigned short* __restrict__ wTq, unsigned short* __restrict__ pTq)
{
  int e = blockIdx.x * 256 + threadIdx.x;   // 262144
  if (e < 196608) {
    int c = e >> 13;                 // chunk id: nc*8 + kc
    int nc = c >> 3, kc = c & 7;
    int p2 = e & 8191;
    int n = p2 >> 5, cw = p2 & 31;
    int kl = cw ^ (((n >> 1) & 3) << 3);
    wTq[e] = f2bf(qkv_w[(size_t)(kc * 32 + kl) * 768 + nc * 256 + n]);
  } else {
    int e2 = e - 196608;
    int kc = e2 >> 13, p2 = e2 & 8191;
    int n = p2 >> 5, cw = p2 & 31;
    int kl = cw ^ (((n >> 1) & 3) << 3);
    pTq[e2] = f2bf(proj_w[(size_t)(kc * 32 + kl) * 256 + n]);
  }
}

// ---- data prep: f32 -> bf16, pre-swizzled per-chunk gll16 layout ----
__global__ __launch_bounds__(256)
void octa_dprep(const float* __restrict__ data, char* __restrict__ dbf)
{
  int e = blockIdx.x * 256 + threadIdx.x;       // [0, nbm*4096)
  int bm = e >> 12;
  int r = e & 4095;
  int t = r >> 9;
  int rr = r & 511;
  int row = rr >> 2, u = rr & 3;
  int l = u ^ ((row >> 1) & 3);
  const float* src = data + ((size_t)bm * 128 + row) * 256 + t * 32 + l * 8;
  float4 x = *(const float4*)src;
  float4 y = *(const float4*)(src + 4);
  int4 v;
  v.x = (int)pk2(x.x, x.y); v.y = (int)pk2(x.z, x.w);
  v.z = (int)pk2(y.x, y.y); v.w = (int)pk2(y.z, y.w);
  *(int4*)(dbf + (size_t)e * 16) = v;
}

// ---- kernel 1: qkv GEMM, all-gll16 dbuf ----
// q/k: coalesced epilogue via LDS E. v: direct scatter in [h][d][tok] layout
// (attn then loads vT fragments densely with ld16).
#define KQ_A0 0
#define KQ_A1 8192
#define KQ_B0 16384
#define KQ_B1 32768
#define KQ_LDS 49152

__global__ __launch_bounds__(512, 4)
void octa_qkv(const char* __restrict__ dbf, const float* __restrict__ qkv_b,
              const unsigned short* __restrict__ wTq, float* __restrict__ ws,
              char* __restrict__ qg, char* __restrict__ kg, char* __restrict__ vg)
{
  extern __shared__ char smem[];
  const int tid = threadIdx.x, lane = tid & 63, wid = tid >> 6;
  const int ql = lane & 15, lg = lane >> 4;
  const int bm = blockIdx.x / 3, nc = blockIdx.x - bm * 3;
  const int wr = wid >> 2, wc = wid & 3;
  const char* wbase = (const char*)wTq + (size_t)nc * 131072;
  const char* abase = dbf + (size_t)bm * 65536;

  // prologue: stage A0 + B0
  gll16(abase + wid * 1024 + lane * 16, smem + KQ_A0 + wid * 1024);
  gll16(wbase + wid * 1024 + lane * 16, smem + KQ_B0 + wid * 1024);
  gll16(wbase + 8192 + wid * 1024 + lane * 16, smem + KQ_B0 + 8192 + wid * 1024);
  __syncthreads();

  f32x4 acc[4][4];
  #pragma unroll
  for (int m = 0; m < 4; ++m)
    #pragma unroll
    for (int n = 0; n < 4; ++n) acc[m][n] = (f32x4){0.f, 0.f, 0.f, 0.f};

  #pragma unroll
  for (int t = 0; t < 8; ++t) {
    if (t < 7) {
      char* ab1 = smem + (((t + 1) & 1) ? KQ_A1 : KQ_A0);
      char* bb1 = smem + (((t + 1) & 1) ? KQ_B1 : KQ_B0);
      gll16(abase + (size_t)(t + 1) * 8192 + wid * 1024 + lane * 16, ab1 + wid * 1024);
      const char* bsrc = wbase + (size_t)(t + 1) * 16384;
      gll16(bsrc + wid * 1024 + lane * 16, bb1 + wid * 1024);
      gll16(bsrc + 8192 + wid * 1024 + lane * 16, bb1 + 8192 + wid * 1024);
    }
    const char* ab = smem + ((t & 1) ? KQ_A1 : KQ_A0);
    const char* bb = smem + ((t & 1) ? KQ_B1 : KQ_B0);
    bf16x8 af[4], bf[4];
    #pragma unroll
    for (int mt = 0; mt < 4; ++mt) {
      int row = wr * 64 + mt * 16 + ql;
      af[mt] = ld16(ab + row * 64 + ((lg * 16) ^ (((row >> 1) & 3) << 4)));
    }
    #pragma unroll
    for (int nt = 0; nt < 4; ++nt) {
      int n = wc * 64 + nt * 16 + ql;
      bf[nt] = ld16(bb + n * 64 + ((lg * 16) ^ (((n >> 1) & 3) << 4)));
    }
    #pragma unroll
    for (int nt = 0; nt < 4; ++nt)
      #pragma unroll
      for (int mt = 0; mt < 4; ++mt)
        acc[mt][nt] = __builtin_amdgcn_mfma_f32_16x16x32_bf16(af[mt], bf[nt], acc[mt][nt], 0, 0, 0);
    __syncthreads();
  }

  // bias values per nt (col fixed per thread)
  float bv[4];
  #pragma unroll
  for (int nt = 0; nt < 4; ++nt)
    bv[nt] = qkv_b[nc * 256 + wc * 64 + nt * 16 + ql];

  // std partials
  #pragma unroll
  for (int nt = 0; nt < 4; ++nt) {
    float s1 = 0.f, s2 = 0.f;
    #pragma unroll
    for (int mt = 0; mt < 4; ++mt)
      #pragma unroll
      for (int r = 0; r < 4; ++r) {
        float v = acc[mt][nt][r] + bv[nt];
        s1 += v; s2 += v * v;
      }
    s1 += __shfl_xor(s1, 16); s1 += __shfl_xor(s1, 32);
    s2 += __shfl_xor(s2, 16); s2 += __shfl_xor(s2, 32);
    if (lg == 0) {
      int col = wc * 64 + nt * 16 + ql;
      atomicAdd(ws + nc * 256 + col, s1);
      atomicAdd(ws + 768 + nc * 256 + col, s2);
    }
  }

  if (nc == 2) {
    // v: direct scatter, transposed layout [w][h][d 32][tok 40] bf16 (80 B rows)
    #pragma unroll
    for (int nt = 0; nt < 4; ++nt) {
      int col = wc * 64 + nt * 16 + ql;
      int h = col >> 5, d = col & 31;
      #pragma unroll
      for (int mt = 0; mt < 4; ++mt) {
        int tg0 = bm * 128 + wr * 64 + mt * 16 + lg * 4;   // 4-aligned within window
        int w = tg0 / 40, tk0 = tg0 - w * 40;
        *(uint2*)(vg + (size_t)(w * 8 + h) * 2560 + d * 80 + tk0 * 2) =
            make_uint2(pk2(acc[mt][nt][0] + bv[nt], acc[mt][nt][1] + bv[nt]),
                       pk2(acc[mt][nt][2] + bv[nt], acc[mt][nt][3] + bv[nt]));
      }
    }
  } else {
    // q/k: coalesced store via LDS E[64][256] bf16 (32KB @0), two wr-halves
    char* base = nc == 0 ? qg : kg;
    const float cs = (nc == 0) ? SCALE_F : 1.0f;
    #pragma unroll
    for (int hh = 0; hh < 2; ++hh) {
      if (wr == hh) {
        #pragma unroll
        for (int nt = 0; nt < 4; ++nt) {
          int col = wc * 64 + nt * 16 + ql;
          #pragma unroll
          for (int mt = 0; mt < 4; ++mt)
            #pragma unroll
            for (int r = 0; r < 4; ++r) {
              int lrow = mt * 16 + lg * 4 + r;
              float v = (acc[mt][nt][r] + bv[nt]) * cs;
              *(unsigned short*)(smem + lrow * 512 + ((col * 2) ^ ((lrow & 7) << 4))) = f2bf(v);
            }
        }
      }
      __syncthreads();
      #pragma unroll
      for (int it = 0; it < 4; ++it) {
        int c = it * 512 + tid;             // [0,2048): lrow 64 x cu 32
        int lrow = c >> 5, cu = c & 31;
        int4 val = *(const int4*)(smem + lrow * 512 + ((cu * 16) ^ ((lrow & 7) << 4)));
        int gtok = bm * 128 + hh * 64 + lrow;
        int w = gtok / 40, tk = gtok - w * 40;
        int h = cu >> 2;
        *(int4*)(base + (size_t)(w * 8 + h) * 2560 + tk * 64 + (cu & 3) * 16) = val;
      }
      __syncthreads();
    }
  }
}

// ---- fused attention+proj v3: in-LDS cooperative bias, vT direct ld16 ----
#define F3_LDS 30720

__global__ __launch_bounds__(512, 4)
void octa_attnproj3(const char* __restrict__ qg, const char* __restrict__ kg,
                    const char* __restrict__ vg, const float* __restrict__ maskp,
                    const int* __restrict__ rel_pos, const float* __restrict__ rpe_table,
                    const unsigned short* __restrict__ pTq, const float* __restrict__ proj_b,
                    float* __restrict__ out)
{
  extern __shared__ char smem[];
  const int tid = threadIdx.x, w = blockIdx.x, wid = tid >> 6;
  const int lane = tid & 63, ql = lane & 15, lg = lane >> 4, h = wid;
  const int perm = ql * 64 + lg * 16;
  const int vperm = ql * 80 + lg * 16;
  const char* qb = qg + (size_t)(w * 8 + h) * 2560;
  const char* kb = kg + (size_t)(w * 8 + h) * 2560;
  const char* vb = vg + (size_t)(w * 8 + h) * 2560;

  // fragment loads issued up-front (latency hides under bias phase)
  bf16x8 kf0 = ld16(kb + perm), kf1 = ld16(kb + 1024 + perm), kf2 = ld16(kb + 2048 + perm);
  bf16x8 qf0 = ld16(qb + perm), qf1 = ld16(qb + 1024 + perm), qf2 = ld16(qb + 2048 + perm);
  // vT layout [d 32][tok 40] 80B rows. vA/vB: d=ql / 16+ql, toks lg*8..+8 (0..31).
  // vC/vD: +64 bytes = toks 32..39 for lg==0; lg>=1 reads neighboring-row data
  //        (finite bf16) which multiplies P=0 -> exact 0. No zero-fill needed.
  bf16x8 vA = ld16(vb + vperm);
  bf16x8 vB = ld16(vb + 1280 + vperm);
  bf16x8 vC = ld16(vb + 64 + vperm);
  bf16x8 vD = ld16(vb + 1280 + 64 + vperm);

  // phase 0: cooperative bias -> BIAS[h][kj][qi] bf16 (rpe rows from global)
  for (int e = tid; e < 1600; e += 512) {
    int qi = e / 40, kj = e - qi * 40;
    float m = maskp[(size_t)w * 1600 + e];
    float b8[8];
    if (qi >= 8 && kj >= 8) {
      const int* rp = rel_pos + ((size_t)w * 1024 + (qi - 8) * 32 + (kj - 8)) * 3;
      int c0 = rp[0], c1 = rp[1], c2 = rp[2];
      c0 = min(25, max(-25, c0)); c1 = min(25, max(-25, c1)); c2 = min(25, max(-25, c2));
      const float4* r0 = (const float4*)(rpe_table + (c0 + 25) * 8);
      const float4* r1 = (const float4*)(rpe_table + (c1 + 76) * 8);
      const float4* r2 = (const float4*)(rpe_table + (c2 + 127) * 8);
      float4 a0 = r0[0], a1 = r1[0], a2 = r2[0];
      float4 b0 = r0[1], b1 = r1[1], b2 = r2[1];
      b8[0] = m + a0.x + a1.x + a2.x; b8[1] = m + a0.y + a1.y + a2.y;
      b8[2] = m + a0.z + a1.z + a2.z; b8[3] = m + a0.w + a1.w + a2.w;
      b8[4] = m + b0.x + b1.x + b2.x; b8[5] = m + b0.y + b1.y + b2.y;
      b8[6] = m + b0.z + b1.z + b2.z; b8[7] = m + b0.w + b1.w + b2.w;
    } else {
      #pragma unroll
      for (int hh = 0; hh < 8; ++hh) b8[hh] = m;
    }
    #pragma unroll
    for (int hh = 0; hh < 8; ++hh)
      *(unsigned short*)(smem + hh * 3200 + kj * 80 + qi * 2) = f2bf(b8[hh]);
  }

  // QK^T (register-only): ST[kj][qi] = mfma(A=k, B=q)
  f32x4 st[9];
  {
    bf16x8 kf[3] = {kf0, kf1, kf2}, qf[3] = {qf0, qf1, qf2};
    __builtin_amdgcn_s_setprio(1);
    #pragma unroll
    for (int a = 0; a < 3; ++a)
      #pragma unroll
      for (int b = 0; b < 3; ++b)
        st[a * 3 + b] = __builtin_amdgcn_mfma_f32_16x16x32_bf16(
            kf[a], qf[b], (f32x4){0.f, 0.f, 0.f, 0.f}, 0, 0, 0);
    __builtin_amdgcn_s_setprio(0);
  }
  __syncthreads();   // B1: bias visible

  const char* bb_ = smem + h * 3200;
  float mx[3] = {-3e38f, -3e38f, -3e38f};
  #pragma unroll
  for (int a = 0; a < 3; ++a) {
    #pragma unroll
    for (int b = 0; b < 3; ++b) {
      #pragma unroll
      for (int r = 0; r < 4; ++r) {
        int kj = a * 16 + lg * 4 + r;
        int qi = b * 16 + ql;
        float s = st[a * 3 + b][r];
        if (kj < 40) {
          if (qi < 40)
            s += bf2f(*(const unsigned short*)(bb_ + kj * 80 + qi * 2));
        } else {
          s = -1e30f;
        }
        st[a * 3 + b][r] = s;
        mx[b] = fmaxf(mx[b], s);
      }
    }
  }
  __syncthreads();   // B2: bias reads done -> P region writable

  #pragma unroll
  for (int b = 0; b < 3; ++b) {
    mx[b] = fmaxf(mx[b], __shfl_xor(mx[b], 16));
    mx[b] = fmaxf(mx[b], __shfl_xor(mx[b], 32));
  }
  float sum[3] = {0.f, 0.f, 0.f};
  #pragma unroll
  for (int a = 0; a < 3; ++a)
    #pragma unroll
    for (int b = 0; b < 3; ++b)
      #pragma unroll
      for (int r = 0; r < 4; ++r) {
        float e = __expf(st[a * 3 + b][r] - mx[b]);
        st[a * 3 + b][r] = e;
        sum[b] += e;
      }
  float inv[3];
  #pragma unroll
  for (int b = 0; b < 3; ++b) {
    sum[b] += __shfl_xor(sum[b], 16);
    sum[b] += __shfl_xor(sum[b], 32);
    inv[b] = 1.f / sum[b];
  }

  char* pb_ = smem + wid * 3840;
  f32x4 ot[6];
  #pragma unroll
  for (int i = 0; i < 6; ++i) ot[i] = (f32x4){0.f, 0.f, 0.f, 0.f};

  #pragma unroll
  for (int a = 0; a < 2; ++a)
    #pragma unroll
    for (int b = 0; b < 3; ++b)
      #pragma unroll
      for (int r = 0; r < 4; ++r) {
        int kj = a * 16 + lg * 4 + r, qi = b * 16 + ql;
        *(unsigned short*)(pb_ + qi * 80 + kj * 2) = f2bf(st[a * 3 + b][r] * inv[b]);
      }
  asm volatile("" ::: "memory");
  __builtin_amdgcn_s_setprio(1);
  #pragma unroll
  for (int b = 0; b < 3; ++b) {
    bf16x8 pf = ld16(pb_ + (b * 16 + ql) * 80 + lg * 16);
    ot[b]     = __builtin_amdgcn_mfma_f32_16x16x32_bf16(vA, pf, ot[b], 0, 0, 0);
    ot[3 + b] = __builtin_amdgcn_mfma_f32_16x16x32_bf16(vB, pf, ot[3 + b], 0, 0, 0);
  }
  __builtin_amdgcn_s_setprio(0);
  asm volatile("" ::: "memory");
  #pragma unroll
  for (int b = 0; b < 3; ++b) {
    int qi = b * 16 + ql;
    #pragma unroll
    for (int r = 0; r < 4; ++r)
      *(unsigned short*)(pb_ + qi * 80 + (lg * 4 + r) * 2) = f2bf(st[6 + b][r] * inv[b]);
    *(uint2*)(pb_ + qi * 80 + 32 + lg * 8) = make_uint2(0u, 0u);
  }
  asm volatile("" ::: "memory");
  __builtin_amdgcn_s_setprio(1);
  #pragma unroll
  for (int b = 0; b < 3; ++b) {
    bf16x8 pf = ld16(pb_ + (b * 16 + ql) * 80 + lg * 16);
    ot[b]     = __builtin_amdgcn_mfma_f32_16x16x32_bf16(vC, pf, ot[b], 0, 0, 0);
    ot[3 + b] = __builtin_amdgcn_mfma_f32_16x16x32_bf16(vD, pf, ot[3 + b], 0, 0, 0);
  }
  __builtin_amdgcn_s_setprio(0);

  __syncthreads();   // B3: P dead
  #pragma unroll
  for (int dm = 0; dm < 2; ++dm)
    #pragma unroll
    for (int b = 0; b < 3; ++b) {
      int qi = b * 16 + ql;
      unsigned u0 = pk2(ot[dm * 3 + b][0], ot[dm * 3 + b][1]);
      unsigned u1 = pk2(ot[dm * 3 + b][2], ot[dm * 3 + b][3]);
      int colb = (h * 32 + dm * 16 + lg * 4) * 2;
      *(uint2*)(smem + qi * 512 + (colb ^ ((qi & 7) << 4))) = make_uint2(u0, u1);
    }
  __syncthreads();   // B4: s_o visible

  f32x4 pacc[3][2];
  #pragma unroll
  for (int m = 0; m < 3; ++m)
    #pragma unroll
    for (int n = 0; n < 2; ++n) pacc[m][n] = (f32x4){0.f, 0.f, 0.f, 0.f};
  const int c0 = wid * 32;
  const char* pB = (const char*)pTq;

  #pragma unroll
  for (int t = 0; t < 8; ++t) {
    bf16x8 af[3], bfr[2];
    #pragma unroll
    for (int mt = 0; mt < 3; ++mt) {
      int row = mt * 16 + ql;
      af[mt] = ld16(smem + row * 512 + ((t * 64 + lg * 16) ^ ((row & 7) << 4)));
    }
    #pragma unroll
    for (int nt = 0; nt < 2; ++nt) {
      int n = c0 + nt * 16 + ql;
      bfr[nt] = ld16(pB + (size_t)t * 16384 + n * 64 + ((lg * 16) ^ (((n >> 1) & 3) << 4)));
    }
    __builtin_amdgcn_s_setprio(1);
    #pragma unroll
    for (int nt = 0; nt < 2; ++nt)
      #pragma unroll
      for (int mt = 0; mt < 3; ++mt)
        pacc[mt][nt] = __builtin_amdgcn_mfma_f32_16x16x32_bf16(af[mt], bfr[nt], pacc[mt][nt], 0, 0, 0);
    __builtin_amdgcn_s_setprio(0);
  }

  #pragma unroll
  for (int nt = 0; nt < 2; ++nt) {
    int col = c0 + nt * 16 + ql;
    float pb = proj_b[col];
    #pragma unroll
    for (int mt = 0; mt < 3; ++mt)
      #pragma unroll
      for (int r = 0; r < 4; ++r) {
        int row = mt * 16 + lg * 4 + r;
        if (row < 40)
          out[(size_t)(w * 40 + row) * 256 + col] = pacc[mt][nt][r] + pb;
      }
  }
}

// ---- std finalize (all paths) ----
__global__ void octa_std(const float* __restrict__ ws, float* __restrict__ out,
                         int total_rows, size_t off)
{
  int j = blockIdx.x * 256 + threadIdx.x;
  if (j < 768) {
    float s = ws[j], ss = ws[768 + j];
    float T = (float)total_rows;
    float var = (ss - s * s / T) / (T - 1.f);
    out[off + j] = sqrtf(fmaxf(var, 0.f));
  }
}

// =======================================================================
// FALLBACK PATH: round-4 fused kernel (verified), used if ws too small
// =======================================================================
#define O_RPE 0
#define O_MSK 4896
#define O_IDX 8096
#define O_A   12192
#define O_ATT 36768
#define B1_SZ 49152
#define ATT_STRIDE 11776
#define AK 3840
#define AV 7680
#define B2_S (O_ATT + 94208)
#define B2_A O_ATT
#define LDS_BYTES_V4 163744

__device__ __forceinline__ int a_addr(int row, int byte) {
  return O_A + row * 512 + (byte ^ ((row & 7) << 4));
}
__device__ __forceinline__ int v_addr(int d, int byte) {
  return AV + d * 128 + (byte ^ ((d & 7) << 4));
}

__global__ void octa_prep_v4(const float* __restrict__ qkv_w, const float* __restrict__ proj_w,
                             unsigned short* __restrict__ wTq, unsigned short* __restrict__ pTq)
{
  int idx = blockIdx.x * 256 + threadIdx.x;
  if (idx < 196608) {
    int n = idx >> 8, k = idx & 255;
    wTq[idx] = f2bf(qkv_w[k * 768 + n]);
  } else {
    int i = idx - 196608;
    int n = i >> 8, k = i & 255;
    pTq[i] = f2bf(proj_w[k * 256 + n]);
  }
}

__global__ __launch_bounds__(512, 2)
void octa_main_v4(const float* __restrict__ data, const int* __restrict__ rel_pos,
                  const float* __restrict__ maskp, const float* __restrict__ qkv_b,
                  const float* __restrict__ proj_b, const float* __restrict__ rpe_table,
                  const unsigned short* __restrict__ wTq, const unsigned short* __restrict__ pTq,
                  float* __restrict__ ws, float* __restrict__ out)
{
  extern __shared__ char smem[];
  float* s_rpe = (float*)(smem + O_RPE);
  const int tid = threadIdx.x;
  const int w   = blockIdx.x;
  const int wid = tid >> 6;
  const int lane = tid & 63;
  const int ql = lane & 15;
  const int lg = lane >> 4;
  const int h  = wid;
  const int ab = O_ATT + wid * ATT_STRIDE;

  {
    #pragma unroll
    for (int it = 0; it < 6; ++it) {
      int g = it * 512 + tid;
      int n = g >> 2, slot = g & 3;
      const char* src = (const char*)wTq + (size_t)n * 512 + ((slot * 16) ^ ((n & 3) << 4));
      gll16(src, smem + O_ATT + it * 8192 + wid * 1024);
    }
  }
  for (int f = tid; f < 1224; f += 512) s_rpe[f] = rpe_table[f];
  for (int f = tid; f < 400; f += 512) {
    float4 m4 = ((const float4*)(maskp + (size_t)w * 1600))[f];
    uint2 pk;
    pk.x = pk2(m4.x, m4.y); pk.y = pk2(m4.z, m4.w);
    *(uint2*)(smem + O_MSK + f * 8) = pk;
  }
  for (int p = tid; p < 1024; p += 512) {
    const int* rp = rel_pos + ((size_t)w * 1024 + p) * 3;
    int c0 = rp[0], c1 = rp[1], c2 = rp[2];
    c0 = min(25, max(-25, c0)); c1 = min(25, max(-25, c1)); c2 = min(25, max(-25, c2));
    unsigned pk = (unsigned)(c0 + 25) | ((unsigned)(c1 + 76) << 10) | ((unsigned)(c2 + 127) << 20);
    *(unsigned*)(smem + O_IDX + ((p * 4) ^ (((p >> 5) & 7) << 4))) = pk;
  }
  {
    const float4* src = (const float4*)(data + (size_t)w * 10240);
    for (int f = tid; f < 2560; f += 512) {
      int token = f >> 6, q4 = f & 63;
      float4 d4 = src[f];
      uint2 pk;
      pk.x = pk2(d4.x, d4.y); pk.y = pk2(d4.z, d4.w);
      *(uint2*)(smem + a_addr(token, q4 * 8)) = pk;
    }
    int token = 40 + (tid >> 6), byte = (tid & 63) * 8;
    *(uint2*)(smem + a_addr(token, byte)) = make_uint2(0u, 0u);
  }
  __syncthreads();

  f32x4 acc[18];
  #pragma unroll
  for (int i = 0; i < 18; ++i) acc[i] = (f32x4){0.f, 0.f, 0.f, 0.f};

  for (int t = 0; t < 8; ++t) {
    if (t < 7) {
      int bb = O_ATT + ((t + 1) & 1) * B1_SZ;
      #pragma unroll
      for (int it = 0; it < 6; ++it) {
        int g = it * 512 + tid;
        int n = g >> 2, slot = g & 3;
        const char* src = (const char*)wTq + (size_t)n * 512 + (t + 1) * 64
                          + ((slot * 16) ^ ((n & 3) << 4));
        gll16(src, smem + bb + it * 8192 + wid * 1024);
      }
    }
    const int bb = O_ATT + (t & 1) * B1_SZ;
    bf16x8 af[3];
    #pragma unroll
    for (int mt = 0; mt < 3; ++mt)
      af[mt] = ld16(smem + a_addr(mt * 16 + ql, t * 64 + lg * 16));
    #pragma unroll
    for (int j = 0; j < 6; ++j) {
      int n = ((j >> 1) * 16 + 2 * wid + (j & 1)) * 16 + ql;
      bf16x8 bf = ld16(smem + bb + n * 64 + ((lg * 16) ^ ((n & 3) << 4)));
      #pragma unroll
      for (int mt = 0; mt < 3; ++mt)
        acc[j * 3 + mt] = __builtin_amdgcn_mfma_f32_16x16x32_bf16(af[mt], bf, acc[j * 3 + mt], 0, 0, 0);
    }
    __syncthreads();
  }

  {
    #pragma unroll
    for (int it = 0; it < 4; ++it) {
      int g = it * 512 + tid;
      int n = g >> 3, slot = g & 7;
      const char* src = (const char*)pTq + (size_t)n * 512 + ((slot * 16) ^ ((n & 7) << 4));
      gll16(src, smem + B2_S + it * 8192 + wid * 1024);
    }
  }

  #pragma unroll
  for (int j = 0; j < 6; ++j) {
    int sec = j >> 1;
    int ncol = sec * 256 + 32 * wid + (j & 1) * 16 + ql;
    int d = (j & 1) * 16 + ql;
    float bias = qkv_b[ncol];
    float s1 = 0.f, s2 = 0.f;
    #pragma unroll
    for (int mt = 0; mt < 3; ++mt) {
      #pragma unroll
      for (int r = 0; r < 4; ++r) {
        int token = mt * 16 + lg * 4 + r;
        float v = acc[j * 3 + mt][r] + bias;
        if (token < 40) { s1 += v; s2 += v * v; }
        if (sec == 0)
          *(unsigned short*)(smem + ab + token * 80 + d * 2) = f2bf(v * SCALE_F);
        else if (sec == 1)
          *(unsigned short*)(smem + ab + AK + token * 80 + d * 2) = f2bf(v);
        else
          *(unsigned short*)(smem + ab + v_addr(d, token * 2)) = f2bf(v);
      }
    }
    s1 += __shfl_xor(s1, 16); s1 += __shfl_xor(s1, 32);
    s2 += __shfl_xor(s2, 16); s2 += __shfl_xor(s2, 32);
    if (lg == 0) { atomicAdd(ws + ncol, s1); atomicAdd(ws + 768 + ncol, s2); }
  }
  {
    int zd = lane >> 1;
    int zb = 96 + (lane & 1) * 16;
    *(int4*)(smem + ab + v_addr(zd, zb)) = (int4){0, 0, 0, 0};
  }
  asm volatile("" ::: "memory");

  f32x4 st[9];
  {
    bf16x8 kf[3], qf[3];
    #pragma unroll
    for (int a = 0; a < 3; ++a) kf[a] = ld16(smem + ab + AK + (a * 16 + ql) * 80 + lg * 16);
    #pragma unroll
    for (int b = 0; b < 3; ++b) qf[b] = ld16(smem + ab + (b * 16 + ql) * 80 + lg * 16);
    #pragma unroll
    for (int a = 0; a < 3; ++a)
      #pragma unroll
      for (int b = 0; b < 3; ++b)
        st[a * 3 + b] = __builtin_amdgcn_mfma_f32_16x16x32_bf16(
            kf[a], qf[b], (f32x4){0.f, 0.f, 0.f, 0.f}, 0, 0, 0);
  }

  float mx[3] = {-3e38f, -3e38f, -3e38f};
  #pragma unroll
  for (int a = 0; a < 3; ++a) {
    #pragma unroll
    for (int b = 0; b < 3; ++b) {
      #pragma unroll
      for (int r = 0; r < 4; ++r) {
        int kj = a * 16 + lg * 4 + r;
        int qi = b * 16 + ql;
        float s = st[a * 3 + b][r];
        if (kj < 40) {
          if (qi < 40) {
            s += bf2f(*(const unsigned short*)(smem + O_MSK + (qi * 40 + kj) * 2));
            if (kj >= 8 && qi >= 8) {
              int p = (qi - 8) * 32 + (kj - 8);
              unsigned pk = *(const unsigned*)(smem + O_IDX + ((p * 4) ^ (((p >> 5) & 7) << 4)));
              s += s_rpe[(pk & 1023) * 8 + h] + s_rpe[((pk >> 10) & 1023) * 8 + h]
                 + s_rpe[(pk >> 20) * 8 + h];
            }
          }
        } else {
          s = -1e30f;
        }
        st[a * 3 + b][r] = s;
        mx[b] = fmaxf(mx[b], s);
      }
    }
  }
  #pragma unroll
  for (int b = 0; b < 3; ++b) {
    mx[b] = fmaxf(mx[b], __shfl_xor(mx[b], 16));
    mx[b] = fmaxf(mx[b], __shfl_xor(mx[b], 32));
  }
  float sum[3] = {0.f, 0.f, 0.f};
  #pragma unroll
  for (int a = 0; a < 3; ++a)
    #pragma unroll
    for (int b = 0; b < 3; ++b)
      #pragma unroll
      for (int r = 0; r < 4; ++r) {
        float e = __expf(st[a * 3 + b][r] - mx[b]);
        st[a * 3 + b][r] = e;
        sum[b] += e;
      }
  float inv[3];
  #pragma unroll
  for (int b = 0; b < 3; ++b) {
    sum[b] += __shfl_xor(sum[b], 16);
    sum[b] += __shfl_xor(sum[b], 32);
    inv[b] = 1.f / sum[b];
  }

  f32x4 ot[6];
  #pragma unroll
  for (int i = 0; i < 6; ++i) ot[i] = (f32x4){0.f, 0.f, 0.f, 0.f};

  #pragma unroll
  for (int a = 0; a < 2; ++a)
    #pragma unroll
    for (int b = 0; b < 3; ++b)
      #pragma unroll
      for (int r = 0; r < 4; ++r) {
        int kj = a * 16 + lg * 4 + r, qi = b * 16 + ql;
        *(unsigned short*)(smem + ab + qi * 80 + kj * 2) = f2bf(st[a * 3 + b][r] * inv[b]);
      }
  asm volatile("" ::: "memory");
  {
    bf16x8 vf0 = ld16(smem + ab + v_addr(ql, lg * 16));
    bf16x8 vf1 = ld16(smem + ab + v_addr(16 + ql, lg * 16));
    #pragma unroll
    for (int b = 0; b < 3; ++b) {
      bf16x8 pf = ld16(smem + ab + (b * 16 + ql) * 80 + lg * 16);
      ot[b] = __builtin_amdgcn_mfma_f32_16x16x32_bf16(vf0, pf, ot[b], 0, 0, 0);
      ot[3 + b] = __builtin_amdgcn_mfma_f32_16x16x32_bf16(vf1, pf, ot[3 + b], 0, 0, 0);
    }
  }
  asm volatile("" ::: "memory");
  #pragma unroll
  for (int b = 0; b < 3; ++b) {
    int qi = b * 16 + ql;
    #pragma unroll
    for (int r = 0; r < 4; ++r) {
      int kj = 32 + lg * 4 + r;
      *(unsigned short*)(smem + ab + qi * 80 + (kj - 32) * 2) = f2bf(st[6 + b][r] * inv[b]);
    }
    *(uint2*)(smem + ab + qi * 80 + 32 + lg * 8) = make_uint2(0u, 0u);
  }
  asm volatile("" ::: "memory");
  {
    bf16x8 vf0 = ld16(smem + ab + v_addr(ql, 64 + lg * 16));
    bf16x8 vf1 = ld16(smem + ab + v_addr(16 + ql, 64 + lg * 16));
    #pragma unroll
    for (int b = 0; b < 3; ++b) {
      bf16x8 pf = ld16(smem + ab + (b * 16 + ql) * 80 + lg * 16);
      ot[b] = __builtin_amdgcn_mfma_f32_16x16x32_bf16(vf0, pf, ot[b], 0, 0, 0);
      ot[3 + b] = __builtin_amdgcn_mfma_f32_16x16x32_bf16(vf1, pf, ot[3 + b], 0, 0, 0);
    }
  }
  #pragma unroll
  for (int dm = 0; dm < 2; ++dm)
    #pragma unroll
    for (int b = 0; b < 3; ++b)
      #pragma unroll
      for (int r = 0; r < 4; ++r) {
        int d = dm * 16 + lg * 4 + r;
        int qi = b * 16 + ql;
        *(unsigned short*)(smem + a_addr(qi, (h * 32 + d) * 2)) = f2bf(ot[dm * 3 + b][r]);
      }
  __syncthreads();

  f32x4 oacc[6];
  #pragma unroll
  for (int i = 0; i < 6; ++i) oacc[i] = (f32x4){0.f, 0.f, 0.f, 0.f};

  for (int t = 0; t < 4; ++t) {
    if (t < 3) {
      int bb = ((t + 1) & 1) ? B2_A : B2_S;
      #pragma unroll
      for (int it = 0; it < 4; ++it) {
        int g = it * 512 + tid;
        int n = g >> 3, slot = g & 7;
        const char* src = (const char*)pTq + (size_t)n * 512 + (t + 1) * 128
                          + ((slot * 16) ^ ((n & 7) << 4));
        gll16(src, smem + bb + it * 8192 + wid * 1024);
      }
    }
    const int bb = (t & 1) ? B2_A : B2_S;
    #pragma unroll
    for (int ks = 0; ks < 2; ++ks) {
      bf16x8 af[3];
      #pragma unroll
      for (int mt = 0; mt < 3; ++mt)
        af[mt] = ld16(smem + a_addr(mt * 16 + ql, t * 128 + ks * 64 + lg * 16));
      #pragma unroll
      for (int nt = 0; nt < 2; ++nt) {
        int n = (2 * wid + nt) * 16 + ql;
        bf16x8 bf = ld16(smem + bb + n * 128 + ((ks * 64 + lg * 16) ^ ((n & 7) << 4)));
        #pragma unroll
        for (int mt = 0; mt < 3; ++mt)
          oacc[nt * 3 + mt] = __builtin_amdgcn_mfma_f32_16x16x32_bf16(af[mt], bf, oacc[nt * 3 + mt], 0, 0, 0);
      }
    }
    __syncthreads();
  }

  #pragma unroll
  for (int nt = 0; nt < 2; ++nt) {
    int ncol = (2 * wid + nt) * 16 + ql;
    float pb = proj_b[ncol];
    #pragma unroll
    for (int mt = 0; mt < 3; ++mt)
      #pragma unroll
      for (int r = 0; r < 4; ++r) {
        int token = mt * 16 + lg * 4 + r;
        if (token < 40)
          out[(size_t)w * 10240 + token * 256 + ncol] = oacc[nt * 3 + mt][r] + pb;
      }
  }
}

// =======================================================================
extern "C" void kernel_launch(void* const* d_in, const int* in_sizes, int n_in,
                              void* d_out, int out_size, void* d_ws, size_t ws_size,
                              hipStream_t stream) {
  const float* data    = (const float*)d_in[0];
  const int*   rel_pos = (const int*)d_in[1];
  const float* maskp   = (const float*)d_in[2];
  const float* qkv_w   = (const float*)d_in[3];
  const float* qkv_b   = (const float*)d_in[4];
  const float* proj_w  = (const float*)d_in[5];
  const float* proj_b  = (const float*)d_in[6];
  const float* rpe_tab = (const float*)d_in[7];
  float* out = (float*)d_out;
  float* ws  = (float*)d_ws;

  const int nw = in_sizes[1] / 3072;           // 4096
  const int total_rows = nw * 40;
  const size_t std_off = (size_t)nw * 10240;
  const size_t SZ = 83886080ull;               // one q/k/v tensor, bf16
  const int nbm = nw * 40 / 128;               // 1280

  const size_t WS1 = 530432ull + 3ull * SZ + 4096ull;

  unsigned short* wTq = (unsigned short*)((char*)d_ws + 6144);
  unsigned short* pTq = (unsigned short*)((char*)d_ws + 399360);

  hipMemsetAsync(ws, 0, 6144, stream);

  if (ws_size >= WS1) {
    char* qg = (char*)d_ws + 530432;
    char* kg = qg + SZ;
    char* vg = kg + SZ;
    char* dbf = (char*)d_out;                  // 84 MB staging: dead after qkv,
                                               // overwritten by attnproj3's out-write
    (void)hipFuncSetAttribute((const void*)octa_attnproj3,
                              hipFuncAttributeMaxDynamicSharedMemorySize, F3_LDS);
    hipLaunchKernelGGL(octa_prep2, dim3(1024), dim3(256), 0, stream, qkv_w, proj_w, wTq, pTq);
    hipLaunchKernelGGL(octa_dprep, dim3(nbm * 16), dim3(256), 0, stream, data, dbf);
    hipLaunchKernelGGL(octa_qkv, dim3(nbm * 3), dim3(512), KQ_LDS, stream,
                       dbf, qkv_b, wTq, ws, qg, kg, vg);
    hipLaunchKernelGGL(octa_attnproj3, dim3(nw), dim3(512), F3_LDS, stream,
                       qg, kg, vg, maskp, rel_pos, rpe_tab, pTq, proj_b, out);
    hipLaunchKernelGGL(octa_std, dim3(3), dim3(256), 0, stream, ws, out, total_rows, std_off);
  } else {
    hipLaunchKernelGGL(octa_prep_v4, dim3(1024), dim3(256), 0, stream, qkv_w, proj_w, wTq, pTq);
    (void)hipFuncSetAttribute((const void*)octa_main_v4,
                              hipFuncAttributeMaxDynamicSharedMemorySize, LDS_BYTES_V4);
    hipLaunchKernelGGL(octa_main_v4, dim3(nw), dim3(512), LDS_BYTES_V4, stream,
                       data, rel_pos, maskp, qkv_b, proj_b, rpe_tab, wTq, pTq, ws, out);
    hipLaunchKernelGGL(octa_std, dim3(3), dim3(256), 0, stream, ws, out, total_rows, std_off);
  }
}

// Round 15
// 363.764 us; speedup vs baseline: 1.7408x; 1.7408x over previous
//
#include <hip/hip_runtime.h>
#include <math.h>

// OctreeAttention: C=256, H=8, HD=32, K=32, G=8, W=40, NW=4096, RPE rows=153
#define SCALE_F 0.17677669529663687f  // 32^-0.5

typedef __bf16 bf16x8 __attribute__((ext_vector_type(8)));
typedef float f32x4 __attribute__((ext_vector_type(4)));

__device__ __forceinline__ unsigned short f2bf(float f) {
  unsigned u = __builtin_bit_cast(unsigned, f);
  u = (u + 0x7FFFu + ((u >> 16) & 1u)) >> 16;
  return (unsigned short)u;
}
__device__ __forceinline__ float bf2f(unsigned short u) {
  return __builtin_bit_cast(float, (unsigned)u << 16);
}
__device__ __forceinline__ unsigned pk2(float a, float b) {
  return (unsigned)f2bf(a) | ((unsigned)f2bf(b) << 16);
}
__device__ __forceinline__ bf16x8 ld16(const void* p) {
  int4 v = *(const int4*)p;
  return __builtin_bit_cast(bf16x8, v);
}
__device__ __forceinline__ void gll16(const void* g, void* l) {
  __builtin_amdgcn_global_load_lds(
      (const __attribute__((address_space(1))) unsigned int*)g,
      (__attribute__((address_space(3))) unsigned int*)l, 16, 0, 0);
}

// =======================================================================
// TIER-1 PATH (ws >= 252 MB, proven on this harness)
// =======================================================================

// ---- prep: weights -> bf16, chunked pre-swizzled ----
__global__ void octa_prep2(const float* __restrict__ qkv_w, const float* __restrict__ proj_w,
                           unsigned short* __restrict__ wTq, unsigned short* __restrict__ pTq)
{
  int e = blockIdx.x * 256 + threadIdx.x;   // 262144
  if (e < 196608) {
    int c = e >> 13;                 // chunk id: nc*8 + kc
    int nc = c >> 3, kc = c & 7;
    int p2 = e & 8191;
    int n = p2 >> 5, cw = p2 & 31;
    int kl = cw ^ (((n >> 1) & 3) << 3);
    wTq[e] = f2bf(qkv_w[(size_t)(kc * 32 + kl) * 768 + nc * 256 + n]);
  } else {
    int e2 = e - 196608;
    int kc = e2 >> 13, p2 = e2 & 8191;
    int n = p2 >> 5, cw = p2 & 31;
    int kl = cw ^ (((n >> 1) & 3) << 3);
    pTq[e2] = f2bf(proj_w[(size_t)(kc * 32 + kl) * 256 + n]);
  }
}

// ---- data prep: f32 -> bf16, pre-swizzled per-chunk gll16 layout ----
__global__ __launch_bounds__(256)
void octa_dprep(const float* __restrict__ data, char* __restrict__ dbf)
{
  int e = blockIdx.x * 256 + threadIdx.x;       // [0, nbm*4096)
  int bm = e >> 12;
  int r = e & 4095;
  int t = r >> 9;
  int rr = r & 511;
  int row = rr >> 2, u = rr & 3;
  int l = u ^ ((row >> 1) & 3);
  const float* src = data + ((size_t)bm * 128 + row) * 256 + t * 32 + l * 8;
  float4 x = *(const float4*)src;
  float4 y = *(const float4*)(src + 4);
  int4 v;
  v.x = (int)pk2(x.x, x.y); v.y = (int)pk2(x.z, x.w);
  v.z = (int)pk2(y.x, y.y); v.w = (int)pk2(y.z, y.w);
  *(int4*)(dbf + (size_t)e * 16) = v;
}

// ---- kernel 1: qkv GEMM, all-gll16 dbuf, coalesced epilogue (R13-verified) ----
#define KQ_A0 0
#define KQ_A1 8192
#define KQ_B0 16384
#define KQ_B1 32768
#define KQ_LDS 49152

__global__ __launch_bounds__(512, 4)
void octa_qkv(const char* __restrict__ dbf, const float* __restrict__ qkv_b,
              const unsigned short* __restrict__ wTq, float* __restrict__ ws,
              char* __restrict__ qg, char* __restrict__ kg, char* __restrict__ vg)
{
  extern __shared__ char smem[];
  const int tid = threadIdx.x, lane = tid & 63, wid = tid >> 6;
  const int ql = lane & 15, lg = lane >> 4;
  const int bm = blockIdx.x / 3, nc = blockIdx.x - bm * 3;
  const int wr = wid >> 2, wc = wid & 3;
  const char* wbase = (const char*)wTq + (size_t)nc * 131072;
  const char* abase = dbf + (size_t)bm * 65536;

  // prologue: stage A0 + B0
  gll16(abase + wid * 1024 + lane * 16, smem + KQ_A0 + wid * 1024);
  gll16(wbase + wid * 1024 + lane * 16, smem + KQ_B0 + wid * 1024);
  gll16(wbase + 8192 + wid * 1024 + lane * 16, smem + KQ_B0 + 8192 + wid * 1024);
  __syncthreads();

  f32x4 acc[4][4];
  #pragma unroll
  for (int m = 0; m < 4; ++m)
    #pragma unroll
    for (int n = 0; n < 4; ++n) acc[m][n] = (f32x4){0.f, 0.f, 0.f, 0.f};

  #pragma unroll
  for (int t = 0; t < 8; ++t) {
    if (t < 7) {
      char* ab1 = smem + (((t + 1) & 1) ? KQ_A1 : KQ_A0);
      char* bb1 = smem + (((t + 1) & 1) ? KQ_B1 : KQ_B0);
      gll16(abase + (size_t)(t + 1) * 8192 + wid * 1024 + lane * 16, ab1 + wid * 1024);
      const char* bsrc = wbase + (size_t)(t + 1) * 16384;
      gll16(bsrc + wid * 1024 + lane * 16, bb1 + wid * 1024);
      gll16(bsrc + 8192 + wid * 1024 + lane * 16, bb1 + 8192 + wid * 1024);
    }
    const char* ab = smem + ((t & 1) ? KQ_A1 : KQ_A0);
    const char* bb = smem + ((t & 1) ? KQ_B1 : KQ_B0);
    bf16x8 af[4], bf[4];
    #pragma unroll
    for (int mt = 0; mt < 4; ++mt) {
      int row = wr * 64 + mt * 16 + ql;
      af[mt] = ld16(ab + row * 64 + ((lg * 16) ^ (((row >> 1) & 3) << 4)));
    }
    #pragma unroll
    for (int nt = 0; nt < 4; ++nt) {
      int n = wc * 64 + nt * 16 + ql;
      bf[nt] = ld16(bb + n * 64 + ((lg * 16) ^ (((n >> 1) & 3) << 4)));
    }
    #pragma unroll
    for (int nt = 0; nt < 4; ++nt)
      #pragma unroll
      for (int mt = 0; mt < 4; ++mt)
        acc[mt][nt] = __builtin_amdgcn_mfma_f32_16x16x32_bf16(af[mt], bf[nt], acc[mt][nt], 0, 0, 0);
    __syncthreads();
  }

  // bias values per nt (col fixed per thread)
  float bv[4];
  #pragma unroll
  for (int nt = 0; nt < 4; ++nt)
    bv[nt] = qkv_b[nc * 256 + wc * 64 + nt * 16 + ql];

  // std partials
  #pragma unroll
  for (int nt = 0; nt < 4; ++nt) {
    float s1 = 0.f, s2 = 0.f;
    #pragma unroll
    for (int mt = 0; mt < 4; ++mt)
      #pragma unroll
      for (int r = 0; r < 4; ++r) {
        float v = acc[mt][nt][r] + bv[nt];
        s1 += v; s2 += v * v;
      }
    s1 += __shfl_xor(s1, 16); s1 += __shfl_xor(s1, 32);
    s2 += __shfl_xor(s2, 16); s2 += __shfl_xor(s2, 32);
    if (lg == 0) {
      int col = wc * 64 + nt * 16 + ql;
      atomicAdd(ws + nc * 256 + col, s1);
      atomicAdd(ws + 768 + nc * 256 + col, s2);
    }
  }

  // coalesced store via LDS E[64][256] bf16 (32KB @0), two wr-halves
  char* base = nc == 0 ? qg : (nc == 1 ? kg : vg);
  const float cs = (nc == 0) ? SCALE_F : 1.0f;
  #pragma unroll
  for (int hh = 0; hh < 2; ++hh) {
    if (wr == hh) {
      #pragma unroll
      for (int nt = 0; nt < 4; ++nt) {
        int col = wc * 64 + nt * 16 + ql;
        #pragma unroll
        for (int mt = 0; mt < 4; ++mt)
          #pragma unroll
          for (int r = 0; r < 4; ++r) {
            int lrow = mt * 16 + lg * 4 + r;
            float v = (acc[mt][nt][r] + bv[nt]) * cs;
            *(unsigned short*)(smem + lrow * 512 + ((col * 2) ^ ((lrow & 7) << 4))) = f2bf(v);
          }
      }
    }
    __syncthreads();
    #pragma unroll
    for (int it = 0; it < 4; ++it) {
      int c = it * 512 + tid;             // [0,2048): lrow 64 x cu 32
      int lrow = c >> 5, cu = c & 31;
      int4 val = *(const int4*)(smem + lrow * 512 + ((cu * 16) ^ ((lrow & 7) << 4)));
      int gtok = bm * 128 + hh * 64 + lrow;
      int w = gtok / 40, tk = gtok - w * 40;
      int h = cu >> 2;
      *(int4*)(base + (size_t)(w * 8 + h) * 2560 + tk * 64 + (cu & 3) * 16) = val;
    }
    __syncthreads();
  }
}

// ---- fused attention+proj v3: in-LDS bias (88B rows), P (88B rows) ----
// LDS 33792: BIAS [8 h][40 kj][88 B] @0 (28160, dead after logits) ;
//            P per-wave [48][88 B] x8 @0 (33792, after B2) ;
//            s_o [48][512 B] swz @0 (24576, after B3).
#define F3_LDS 33792

__global__ __launch_bounds__(512, 4)
void octa_attnproj3(const char* __restrict__ qg, const char* __restrict__ kg,
                    const char* __restrict__ vg, const float* __restrict__ maskp,
                    const int* __restrict__ rel_pos, const float* __restrict__ rpe_table,
                    const unsigned short* __restrict__ pTq, const float* __restrict__ proj_b,
                    float* __restrict__ out)
{
  extern __shared__ char smem[];
  const int tid = threadIdx.x, w = blockIdx.x, wid = tid >> 6;
  const int lane = tid & 63, ql = lane & 15, lg = lane >> 4, h = wid;
  const int perm = ql * 64 + lg * 16;
  const char* qb = qg + (size_t)(w * 8 + h) * 2560;
  const char* kb = kg + (size_t)(w * 8 + h) * 2560;
  const char* vb = vg + (size_t)(w * 8 + h) * 2560;

  // fragment loads issued up-front (latency hides under bias phase)
  bf16x8 kf0 = ld16(kb + perm), kf1 = ld16(kb + 1024 + perm), kf2 = ld16(kb + 2048 + perm);
  bf16x8 qf0 = ld16(qb + perm), qf1 = ld16(qb + 1024 + perm), qf2 = ld16(qb + 2048 + perm);
  // vT fragments via scalar gather from the L2-hot 2.5KB v slice ([tok][d] rows)
  union U8 { unsigned short u[8]; bf16x8 v; };
  U8 ua, ub, uc, ud;
  #pragma unroll
  for (int j = 0; j < 8; ++j) {
    int tok = lg * 8 + j;
    ua.u[j] = *(const unsigned short*)(vb + tok * 64 + ql * 2);
    ub.u[j] = *(const unsigned short*)(vb + tok * 64 + (16 + ql) * 2);
  }
  if (lg == 0) {
    #pragma unroll
    for (int j = 0; j < 8; ++j) {
      uc.u[j] = *(const unsigned short*)(vb + (32 + j) * 64 + ql * 2);
      ud.u[j] = *(const unsigned short*)(vb + (32 + j) * 64 + (16 + ql) * 2);
    }
  } else {
    #pragma unroll
    for (int j = 0; j < 8; ++j) { uc.u[j] = 0; ud.u[j] = 0; }
  }
  bf16x8 vA = ua.v, vB = ub.v, vC = uc.v, vD = ud.v;

  // phase 0: cooperative bias -> BIAS[h][kj][qi] bf16, 88B rows (rpe from global)
  for (int e = tid; e < 1600; e += 512) {
    int qi = e / 40, kj = e - qi * 40;
    float m = maskp[(size_t)w * 1600 + e];
    float b8[8];
    if (qi >= 8 && kj >= 8) {
      const int* rp = rel_pos + ((size_t)w * 1024 + (qi - 8) * 32 + (kj - 8)) * 3;
      int c0 = rp[0], c1 = rp[1], c2 = rp[2];
      c0 = min(25, max(-25, c0)); c1 = min(25, max(-25, c1)); c2 = min(25, max(-25, c2));
      const float4* r0 = (const float4*)(rpe_table + (c0 + 25) * 8);
      const float4* r1 = (const float4*)(rpe_table + (c1 + 76) * 8);
      const float4* r2 = (const float4*)(rpe_table + (c2 + 127) * 8);
      float4 a0 = r0[0], a1 = r1[0], a2 = r2[0];
      float4 b0 = r0[1], b1 = r1[1], b2 = r2[1];
      b8[0] = m + a0.x + a1.x + a2.x; b8[1] = m + a0.y + a1.y + a2.y;
      b8[2] = m + a0.z + a1.z + a2.z; b8[3] = m + a0.w + a1.w + a2.w;
      b8[4] = m + b0.x + b1.x + b2.x; b8[5] = m + b0.y + b1.y + b2.y;
      b8[6] = m + b0.z + b1.z + b2.z; b8[7] = m + b0.w + b1.w + b2.w;
    } else {
      #pragma unroll
      for (int hh = 0; hh < 8; ++hh) b8[hh] = m;
    }
    #pragma unroll
    for (int hh = 0; hh < 8; ++hh)
      *(unsigned short*)(smem + hh * 3520 + kj * 88 + qi * 2) = f2bf(b8[hh]);
  }

  // QK^T (register-only): ST[kj][qi] = mfma(A=k, B=q)
  f32x4 st[9];
  {
    bf16x8 kf[3] = {kf0, kf1, kf2}, qf[3] = {qf0, qf1, qf2};
    __builtin_amdgcn_s_setprio(1);
    #pragma unroll
    for (int a = 0; a < 3; ++a)
      #pragma unroll
      for (int b = 0; b < 3; ++b)
        st[a * 3 + b] = __builtin_amdgcn_mfma_f32_16x16x32_bf16(
            kf[a], qf[b], (f32x4){0.f, 0.f, 0.f, 0.f}, 0, 0, 0);
    __builtin_amdgcn_s_setprio(0);
  }
  __syncthreads();   // B1: bias visible

  const char* bb_ = smem + h * 3520;
  float mx[3] = {-3e38f, -3e38f, -3e38f};
  #pragma unroll
  for (int a = 0; a < 3; ++a) {
    #pragma unroll
    for (int b = 0; b < 3; ++b) {
      #pragma unroll
      for (int r = 0; r < 4; ++r) {
        int kj = a * 16 + lg * 4 + r;
        int qi = b * 16 + ql;
        float s = st[a * 3 + b][r];
        if (kj < 40) {
          if (qi < 40)
            s += bf2f(*(const unsigned short*)(bb_ + kj * 88 + qi * 2));
        } else {
          s = -1e30f;
        }
        st[a * 3 + b][r] = s;
        mx[b] = fmaxf(mx[b], s);
      }
    }
  }
  __syncthreads();   // B2: bias reads done -> P region writable

  #pragma unroll
  for (int b = 0; b < 3; ++b) {
    mx[b] = fmaxf(mx[b], __shfl_xor(mx[b], 16));
    mx[b] = fmaxf(mx[b], __shfl_xor(mx[b], 32));
  }
  float sum[3] = {0.f, 0.f, 0.f};
  #pragma unroll
  for (int a = 0; a < 3; ++a)
    #pragma unroll
    for (int b = 0; b < 3; ++b)
      #pragma unroll
      for (int r = 0; r < 4; ++r) {
        float e = __expf(st[a * 3 + b][r] - mx[b]);
        st[a * 3 + b][r] = e;
        sum[b] += e;
      }
  float inv[3];
  #pragma unroll
  for (int b = 0; b < 3; ++b) {
    sum[b] += __shfl_xor(sum[b], 16);
    sum[b] += __shfl_xor(sum[b], 32);
    inv[b] = 1.f / sum[b];
  }

  // PV in two kj-halves; per-wave P buffer @ wid*4224, 88B rows
  char* pb_ = smem + wid * 4224;
  f32x4 ot[6];
  #pragma unroll
  for (int i = 0; i < 6; ++i) ot[i] = (f32x4){0.f, 0.f, 0.f, 0.f};

  #pragma unroll
  for (int a = 0; a < 2; ++a)
    #pragma unroll
    for (int b = 0; b < 3; ++b)
      #pragma unroll
      for (int r = 0; r < 4; ++r) {
        int kj = a * 16 + lg * 4 + r, qi = b * 16 + ql;
        *(unsigned short*)(pb_ + qi * 88 + kj * 2) = f2bf(st[a * 3 + b][r] * inv[b]);
      }
  asm volatile("" ::: "memory");
  __builtin_amdgcn_s_setprio(1);
  #pragma unroll
  for (int b = 0; b < 3; ++b) {
    bf16x8 pf = ld16(pb_ + (b * 16 + ql) * 88 + lg * 16);
    ot[b]     = __builtin_amdgcn_mfma_f32_16x16x32_bf16(vA, pf, ot[b], 0, 0, 0);
    ot[3 + b] = __builtin_amdgcn_mfma_f32_16x16x32_bf16(vB, pf, ot[3 + b], 0, 0, 0);
  }
  __builtin_amdgcn_s_setprio(0);
  asm volatile("" ::: "memory");
  #pragma unroll
  for (int b = 0; b < 3; ++b) {
    int qi = b * 16 + ql;
    #pragma unroll
    for (int r = 0; r < 4; ++r)
      *(unsigned short*)(pb_ + qi * 88 + (lg * 4 + r) * 2) = f2bf(st[6 + b][r] * inv[b]);
    *(uint2*)(pb_ + qi * 88 + 32 + lg * 8) = make_uint2(0u, 0u);
  }
  asm volatile("" ::: "memory");
  __builtin_amdgcn_s_setprio(1);
  #pragma unroll
  for (int b = 0; b < 3; ++b) {
    bf16x8 pf = ld16(pb_ + (b * 16 + ql) * 88 + lg * 16);
    ot[b]     = __builtin_amdgcn_mfma_f32_16x16x32_bf16(vC, pf, ot[b], 0, 0, 0);
    ot[3 + b] = __builtin_amdgcn_mfma_f32_16x16x32_bf16(vD, pf, ot[3 + b], 0, 0, 0);
  }
  __builtin_amdgcn_s_setprio(0);

  __syncthreads();   // B3: P dead
  #pragma unroll
  for (int dm = 0; dm < 2; ++dm)
    #pragma unroll
    for (int b = 0; b < 3; ++b) {
      int qi = b * 16 + ql;
      unsigned u0 = pk2(ot[dm * 3 + b][0], ot[dm * 3 + b][1]);
      unsigned u1 = pk2(ot[dm * 3 + b][2], ot[dm * 3 + b][3]);
      int colb = (h * 32 + dm * 16 + lg * 4) * 2;
      *(uint2*)(smem + qi * 512 + (colb ^ ((qi & 7) << 4))) = make_uint2(u0, u1);
    }
  __syncthreads();   // B4: s_o visible

  f32x4 pacc[3][2];
  #pragma unroll
  for (int m = 0; m < 3; ++m)
    #pragma unroll
    for (int n = 0; n < 2; ++n) pacc[m][n] = (f32x4){0.f, 0.f, 0.f, 0.f};
  const int c0 = wid * 32;
  const char* pB = (const char*)pTq;

  #pragma unroll
  for (int t = 0; t < 8; ++t) {
    bf16x8 af[3], bfr[2];
    #pragma unroll
    for (int mt = 0; mt < 3; ++mt) {
      int row = mt * 16 + ql;
      af[mt] = ld16(smem + row * 512 + ((t * 64 + lg * 16) ^ ((row & 7) << 4)));
    }
    #pragma unroll
    for (int nt = 0; nt < 2; ++nt) {
      int n = c0 + nt * 16 + ql;
      bfr[nt] = ld16(pB + (size_t)t * 16384 + n * 64 + ((lg * 16) ^ (((n >> 1) & 3) << 4)));
    }
    __builtin_amdgcn_s_setprio(1);
    #pragma unroll
    for (int nt = 0; nt < 2; ++nt)
      #pragma unroll
      for (int mt = 0; mt < 3; ++mt)
        pacc[mt][nt] = __builtin_amdgcn_mfma_f32_16x16x32_bf16(af[mt], bfr[nt], pacc[mt][nt], 0, 0, 0);
    __builtin_amdgcn_s_setprio(0);
  }

  #pragma unroll
  for (int nt = 0; nt < 2; ++nt) {
    int col = c0 + nt * 16 + ql;
    float pb = proj_b[col];
    #pragma unroll
    for (int mt = 0; mt < 3; ++mt)
      #pragma unroll
      for (int r = 0; r < 4; ++r) {
        int row = mt * 16 + lg * 4 + r;
        if (row < 40)
          out[(size_t)(w * 40 + row) * 256 + col] = pacc[mt][nt][r] + pb;
      }
  }
}

// ---- std finalize (all paths) ----
__global__ void octa_std(const float* __restrict__ ws, float* __restrict__ out,
                         int total_rows, size_t off)
{
  int j = blockIdx.x * 256 + threadIdx.x;
  if (j < 768) {
    float s = ws[j], ss = ws[768 + j];
    float T = (float)total_rows;
    float var = (ss - s * s / T) / (T - 1.f);
    out[off + j] = sqrtf(fmaxf(var, 0.f));
  }
}

// =======================================================================
// FALLBACK PATH: round-4 fused kernel (verified), used if ws too small
// =======================================================================
#define O_RPE 0
#define O_MSK 4896
#define O_IDX 8096
#define O_A   12192
#define O_ATT 36768
#define B1_SZ 49152
#define ATT_STRIDE 11776
#define AK 3840
#define AV 7680
#define B2_S (O_ATT + 94208)
#define B2_A O_ATT
#define LDS_BYTES_V4 163744

__device__ __forceinline__ int a_addr(int row, int byte) {
  return O_A + row * 512 + (byte ^ ((row & 7) << 4));
}
__device__ __forceinline__ int v_addr(int d, int byte) {
  return AV + d * 128 + (byte ^ ((d & 7) << 4));
}

__global__ void octa_prep_v4(const float* __restrict__ qkv_w, const float* __restrict__ proj_w,
                             unsigned short* __restrict__ wTq, unsigned short* __restrict__ pTq)
{
  int idx = blockIdx.x * 256 + threadIdx.x;
  if (idx < 196608) {
    int n = idx >> 8, k = idx & 255;
    wTq[idx] = f2bf(qkv_w[k * 768 + n]);
  } else {
    int i = idx - 196608;
    int n = i >> 8, k = i & 255;
    pTq[i] = f2bf(proj_w[k * 256 + n]);
  }
}

__global__ __launch_bounds__(512, 2)
void octa_main_v4(const float* __restrict__ data, const int* __restrict__ rel_pos,
                  const float* __restrict__ maskp, const float* __restrict__ qkv_b,
                  const float* __restrict__ proj_b, const float* __restrict__ rpe_table,
                  const unsigned short* __restrict__ wTq, const unsigned short* __restrict__ pTq,
                  float* __restrict__ ws, float* __restrict__ out)
{
  extern __shared__ char smem[];
  float* s_rpe = (float*)(smem + O_RPE);
  const int tid = threadIdx.x;
  const int w   = blockIdx.x;
  const int wid = tid >> 6;
  const int lane = tid & 63;
  const int ql = lane & 15;
  const int lg = lane >> 4;
  const int h  = wid;
  const int ab = O_ATT + wid * ATT_STRIDE;

  {
    #pragma unroll
    for (int it = 0; it < 6; ++it) {
      int g = it * 512 + tid;
      int n = g >> 2, slot = g & 3;
      const char* src = (const char*)wTq + (size_t)n * 512 + ((slot * 16) ^ ((n & 3) << 4));
      gll16(src, smem + O_ATT + it * 8192 + wid * 1024);
    }
  }
  for (int f = tid; f < 1224; f += 512) s_rpe[f] = rpe_table[f];
  for (int f = tid; f < 400; f += 512) {
    float4 m4 = ((const float4*)(maskp + (size_t)w * 1600))[f];
    uint2 pk;
    pk.x = pk2(m4.x, m4.y); pk.y = pk2(m4.z, m4.w);
    *(uint2*)(smem + O_MSK + f * 8) = pk;
  }
  for (int p = tid; p < 1024; p += 512) {
    const int* rp = rel_pos + ((size_t)w * 1024 + p) * 3;
    int c0 = rp[0], c1 = rp[1], c2 = rp[2];
    c0 = min(25, max(-25, c0)); c1 = min(25, max(-25, c1)); c2 = min(25, max(-25, c2));
    unsigned pk = (unsigned)(c0 + 25) | ((unsigned)(c1 + 76) << 10) | ((unsigned)(c2 + 127) << 20);
    *(unsigned*)(smem + O_IDX + ((p * 4) ^ (((p >> 5) & 7) << 4))) = pk;
  }
  {
    const float4* src = (const float4*)(data + (size_t)w * 10240);
    for (int f = tid; f < 2560; f += 512) {
      int token = f >> 6, q4 = f & 63;
      float4 d4 = src[f];
      uint2 pk;
      pk.x = pk2(d4.x, d4.y); pk.y = pk2(d4.z, d4.w);
      *(uint2*)(smem + a_addr(token, q4 * 8)) = pk;
    }
    int token = 40 + (tid >> 6), byte = (tid & 63) * 8;
    *(uint2*)(smem + a_addr(token, byte)) = make_uint2(0u, 0u);
  }
  __syncthreads();

  f32x4 acc[18];
  #pragma unroll
  for (int i = 0; i < 18; ++i) acc[i] = (f32x4){0.f, 0.f, 0.f, 0.f};

  for (int t = 0; t < 8; ++t) {
    if (t < 7) {
      int bb = O_ATT + ((t + 1) & 1) * B1_SZ;
      #pragma unroll
      for (int it = 0; it < 6; ++it) {
        int g = it * 512 + tid;
        int n = g >> 2, slot = g & 3;
        const char* src = (const char*)wTq + (size_t)n * 512 + (t + 1) * 64
                          + ((slot * 16) ^ ((n & 3) << 4));
        gll16(src, smem + bb + it * 8192 + wid * 1024);
      }
    }
    const int bb = O_ATT + (t & 1) * B1_SZ;
    bf16x8 af[3];
    #pragma unroll
    for (int mt = 0; mt < 3; ++mt)
      af[mt] = ld16(smem + a_addr(mt * 16 + ql, t * 64 + lg * 16));
    #pragma unroll
    for (int j = 0; j < 6; ++j) {
      int n = ((j >> 1) * 16 + 2 * wid + (j & 1)) * 16 + ql;
      bf16x8 bf = ld16(smem + bb + n * 64 + ((lg * 16) ^ ((n & 3) << 4)));
      #pragma unroll
      for (int mt = 0; mt < 3; ++mt)
        acc[j * 3 + mt] = __builtin_amdgcn_mfma_f32_16x16x32_bf16(af[mt], bf, acc[j * 3 + mt], 0, 0, 0);
    }
    __syncthreads();
  }

  {
    #pragma unroll
    for (int it = 0; it < 4; ++it) {
      int g = it * 512 + tid;
      int n = g >> 3, slot = g & 7;
      const char* src = (const char*)pTq + (size_t)n * 512 + ((slot * 16) ^ ((n & 7) << 4));
      gll16(src, smem + B2_S + it * 8192 + wid * 1024);
    }
  }

  #pragma unroll
  for (int j = 0; j < 6; ++j) {
    int sec = j >> 1;
    int ncol = sec * 256 + 32 * wid + (j & 1) * 16 + ql;
    int d = (j & 1) * 16 + ql;
    float bias = qkv_b[ncol];
    float s1 = 0.f, s2 = 0.f;
    #pragma unroll
    for (int mt = 0; mt < 3; ++mt) {
      #pragma unroll
      for (int r = 0; r < 4; ++r) {
        int token = mt * 16 + lg * 4 + r;
        float v = acc[j * 3 + mt][r] + bias;
        if (token < 40) { s1 += v; s2 += v * v; }
        if (sec == 0)
          *(unsigned short*)(smem + ab + token * 80 + d * 2) = f2bf(v * SCALE_F);
        else if (sec == 1)
          *(unsigned short*)(smem + ab + AK + token * 80 + d * 2) = f2bf(v);
        else
          *(unsigned short*)(smem + ab + v_addr(d, token * 2)) = f2bf(v);
      }
    }
    s1 += __shfl_xor(s1, 16); s1 += __shfl_xor(s1, 32);
    s2 += __shfl_xor(s2, 16); s2 += __shfl_xor(s2, 32);
    if (lg == 0) { atomicAdd(ws + ncol, s1); atomicAdd(ws + 768 + ncol, s2); }
  }
  {
    int zd = lane >> 1;
    int zb = 96 + (lane & 1) * 16;
    *(int4*)(smem + ab + v_addr(zd, zb)) = (int4){0, 0, 0, 0};
  }
  asm volatile("" ::: "memory");

  f32x4 st[9];
  {
    bf16x8 kf[3], qf[3];
    #pragma unroll
    for (int a = 0; a < 3; ++a) kf[a] = ld16(smem + ab + AK + (a * 16 + ql) * 80 + lg * 16);
    #pragma unroll
    for (int b = 0; b < 3; ++b) qf[b] = ld16(smem + ab + (b * 16 + ql) * 80 + lg * 16);
    #pragma unroll
    for (int a = 0; a < 3; ++a)
      #pragma unroll
      for (int b = 0; b < 3; ++b)
        st[a * 3 + b] = __builtin_amdgcn_mfma_f32_16x16x32_bf16(
            kf[a], qf[b], (f32x4){0.f, 0.f, 0.f, 0.f}, 0, 0, 0);
  }

  float mx[3] = {-3e38f, -3e38f, -3e38f};
  #pragma unroll
  for (int a = 0; a < 3; ++a) {
    #pragma unroll
    for (int b = 0; b < 3; ++b) {
      #pragma unroll
      for (int r = 0; r < 4; ++r) {
        int kj = a * 16 + lg * 4 + r;
        int qi = b * 16 + ql;
        float s = st[a * 3 + b][r];
        if (kj < 40) {
          if (qi < 40) {
            s += bf2f(*(const unsigned short*)(smem + O_MSK + (qi * 40 + kj) * 2));
            if (kj >= 8 && qi >= 8) {
              int p = (qi - 8) * 32 + (kj - 8);
              unsigned pk = *(const unsigned*)(smem + O_IDX + ((p * 4) ^ (((p >> 5) & 7) << 4)));
              s += s_rpe[(pk & 1023) * 8 + h] + s_rpe[((pk >> 10) & 1023) * 8 + h]
                 + s_rpe[(pk >> 20) * 8 + h];
            }
          }
        } else {
          s = -1e30f;
        }
        st[a * 3 + b][r] = s;
        mx[b] = fmaxf(mx[b], s);
      }
    }
  }
  #pragma unroll
  for (int b = 0; b < 3; ++b) {
    mx[b] = fmaxf(mx[b], __shfl_xor(mx[b], 16));
    mx[b] = fmaxf(mx[b], __shfl_xor(mx[b], 32));
  }
  float sum[3] = {0.f, 0.f, 0.f};
  #pragma unroll
  for (int a = 0; a < 3; ++a)
    #pragma unroll
    for (int b = 0; b < 3; ++b)
      #pragma unroll
      for (int r = 0; r < 4; ++r) {
        float e = __expf(st[a * 3 + b][r] - mx[b]);
        st[a * 3 + b][r] = e;
        sum[b] += e;
      }
  float inv[3];
  #pragma unroll
  for (int b = 0; b < 3; ++b) {
    sum[b] += __shfl_xor(sum[b], 16);
    sum[b] += __shfl_xor(sum[b], 32);
    inv[b] = 1.f / sum[b];
  }

  f32x4 ot[6];
  #pragma unroll
  for (int i = 0; i < 6; ++i) ot[i] = (f32x4){0.f, 0.f, 0.f, 0.f};

  #pragma unroll
  for (int a = 0; a < 2; ++a)
    #pragma unroll
    for (int b = 0; b < 3; ++b)
      #pragma unroll
      for (int r = 0; r < 4; ++r) {
        int kj = a * 16 + lg * 4 + r, qi = b * 16 + ql;
        *(unsigned short*)(smem + ab + qi * 80 + kj * 2) = f2bf(st[a * 3 + b][r] * inv[b]);
      }
  asm volatile("" ::: "memory");
  {
    bf16x8 vf0 = ld16(smem + ab + v_addr(ql, lg * 16));
    bf16x8 vf1 = ld16(smem + ab + v_addr(16 + ql, lg * 16));
    #pragma unroll
    for (int b = 0; b < 3; ++b) {
      bf16x8 pf = ld16(smem + ab + (b * 16 + ql) * 80 + lg * 16);
      ot[b] = __builtin_amdgcn_mfma_f32_16x16x32_bf16(vf0, pf, ot[b], 0, 0, 0);
      ot[3 + b] = __builtin_amdgcn_mfma_f32_16x16x32_bf16(vf1, pf, ot[3 + b], 0, 0, 0);
    }
  }
  asm volatile("" ::: "memory");
  #pragma unroll
  for (int b = 0; b < 3; ++b) {
    int qi = b * 16 + ql;
    #pragma unroll
    for (int r = 0; r < 4; ++r) {
      int kj = 32 + lg * 4 + r;
      *(unsigned short*)(smem + ab + qi * 80 + (kj - 32) * 2) = f2bf(st[6 + b][r] * inv[b]);
    }
    *(uint2*)(smem + ab + qi * 80 + 32 + lg * 8) = make_uint2(0u, 0u);
  }
  asm volatile("" ::: "memory");
  {
    bf16x8 vf0 = ld16(smem + ab + v_addr(ql, 64 + lg * 16));
    bf16x8 vf1 = ld16(smem + ab + v_addr(16 + ql, 64 + lg * 16));
    #pragma unroll
    for (int b = 0; b < 3; ++b) {
      bf16x8 pf = ld16(smem + ab + (b * 16 + ql) * 80 + lg * 16);
      ot[b] = __builtin_amdgcn_mfma_f32_16x16x32_bf16(vf0, pf, ot[b], 0, 0, 0);
      ot[3 + b] = __builtin_amdgcn_mfma_f32_16x16x32_bf16(vf1, pf, ot[3 + b], 0, 0, 0);
    }
  }
  #pragma unroll
  for (int dm = 0; dm < 2; ++dm)
    #pragma unroll
    for (int b = 0; b < 3; ++b)
      #pragma unroll
      for (int r = 0; r < 4; ++r) {
        int d = dm * 16 + lg * 4 + r;
        int qi = b * 16 + ql;
        *(unsigned short*)(smem + a_addr(qi, (h * 32 + d) * 2)) = f2bf(ot[dm * 3 + b][r]);
      }
  __syncthreads();

  f32x4 oacc[6];
  #pragma unroll
  for (int i = 0; i < 6; ++i) oacc[i] = (f32x4){0.f, 0.f, 0.f, 0.f};

  for (int t = 0; t < 4; ++t) {
    if (t < 3) {
      int bb = ((t + 1) & 1) ? B2_A : B2_S;
      #pragma unroll
      for (int it = 0; it < 4; ++it) {
        int g = it * 512 + tid;
        int n = g >> 3, slot = g & 7;
        const char* src = (const char*)pTq + (size_t)n * 512 + (t + 1) * 128
                          + ((slot * 16) ^ ((n & 7) << 4));
        gll16(src, smem + bb + it * 8192 + wid * 1024);
      }
    }
    const int bb = (t & 1) ? B2_A : B2_S;
    #pragma unroll
    for (int ks = 0; ks < 2; ++ks) {
      bf16x8 af[3];
      #pragma unroll
      for (int mt = 0; mt < 3; ++mt)
        af[mt] = ld16(smem + a_addr(mt * 16 + ql, t * 128 + ks * 64 + lg * 16));
      #pragma unroll
      for (int nt = 0; nt < 2; ++nt) {
        int n = (2 * wid + nt) * 16 + ql;
        bf16x8 bf = ld16(smem + bb + n * 128 + ((ks * 64 + lg * 16) ^ ((n & 7) << 4)));
        #pragma unroll
        for (int mt = 0; mt < 3; ++mt)
          oacc[nt * 3 + mt] = __builtin_amdgcn_mfma_f32_16x16x32_bf16(af[mt], bf, oacc[nt * 3 + mt], 0, 0, 0);
      }
    }
    __syncthreads();
  }

  #pragma unroll
  for (int nt = 0; nt < 2; ++nt) {
    int ncol = (2 * wid + nt) * 16 + ql;
    float pb = proj_b[ncol];
    #pragma unroll
    for (int mt = 0; mt < 3; ++mt)
      #pragma unroll
      for (int r = 0; r < 4; ++r) {
        int token = mt * 16 + lg * 4 + r;
        if (token < 40)
          out[(size_t)w * 10240 + token * 256 + ncol] = oacc[nt * 3 + mt][r] + pb;
      }
  }
}

// =======================================================================
extern "C" void kernel_launch(void* const* d_in, const int* in_sizes, int n_in,
                              void* d_out, int out_size, void* d_ws, size_t ws_size,
                              hipStream_t stream) {
  const float* data    = (const float*)d_in[0];
  const int*   rel_pos = (const int*)d_in[1];
  const float* maskp   = (const float*)d_in[2];
  const float* qkv_w   = (const float*)d_in[3];
  const float* qkv_b   = (const float*)d_in[4];
  const float* proj_w  = (const float*)d_in[5];
  const float* proj_b  = (const float*)d_in[6];
  const float* rpe_tab = (const float*)d_in[7];
  float* out = (float*)d_out;
  float* ws  = (float*)d_ws;

  const int nw = in_sizes[1] / 3072;           // 4096
  const int total_rows = nw * 40;
  const size_t std_off = (size_t)nw * 10240;
  const size_t SZ = 83886080ull;               // one q/k/v tensor, bf16
  const int nbm = nw * 40 / 128;               // 1280

  const size_t WS1 = 530432ull + 3ull * SZ + 4096ull;

  unsigned short* wTq = (unsigned short*)((char*)d_ws + 6144);
  unsigned short* pTq = (unsigned short*)((char*)d_ws + 399360);

  hipMemsetAsync(ws, 0, 6144, stream);

  if (ws_size >= WS1) {
    char* qg = (char*)d_ws + 530432;
    char* kg = qg + SZ;
    char* vg = kg + SZ;
    char* dbf = (char*)d_out;                  // 84 MB staging: dead after qkv,
                                               // overwritten by attnproj3's out-write
    (void)hipFuncSetAttribute((const void*)octa_attnproj3,
                              hipFuncAttributeMaxDynamicSharedMemorySize, F3_LDS);
    hipLaunchKernelGGL(octa_prep2, dim3(1024), dim3(256), 0, stream, qkv_w, proj_w, wTq, pTq);
    hipLaunchKernelGGL(octa_dprep, dim3(nbm * 16), dim3(256), 0, stream, data, dbf);
    hipLaunchKernelGGL(octa_qkv, dim3(nbm * 3), dim3(512), KQ_LDS, stream,
                       dbf, qkv_b, wTq, ws, qg, kg, vg);
    hipLaunchKernelGGL(octa_attnproj3, dim3(nw), dim3(512), F3_LDS, stream,
                       qg, kg, vg, maskp, rel_pos, rpe_tab, pTq, proj_b, out);
    hipLaunchKernelGGL(octa_std, dim3(3), dim3(256), 0, stream, ws, out, total_rows, std_off);
  } else {
    hipLaunchKernelGGL(octa_prep_v4, dim3(1024), dim3(256), 0, stream, qkv_w, proj_w, wTq, pTq);
    (void)hipFuncSetAttribute((const void*)octa_main_v4,
                              hipFuncAttributeMaxDynamicSharedMemorySize, LDS_BYTES_V4);
    hipLaunchKernelGGL(octa_main_v4, dim3(nw), dim3(512), LDS_BYTES_V4, stream,
                       data, rel_pos, maskp, qkv_b, proj_b, rpe_tab, wTq, pTq, ws, out);
    hipLaunchKernelGGL(octa_std, dim3(3), dim3(256), 0, stream, ws, out, total_rows, std_off);
  }
}

// Round 16
// 352.895 us; speedup vs baseline: 1.7944x; 1.0308x over previous
//
#include <hip/hip_runtime.h>
#include <math.h>

// OctreeAttention: C=256, H=8, HD=32, K=32, G=8, W=40, NW=4096, RPE rows=153
#define SCALE_F 0.17677669529663687f  // 32^-0.5

typedef __bf16 bf16x8 __attribute__((ext_vector_type(8)));
typedef float f32x4 __attribute__((ext_vector_type(4)));

__device__ __forceinline__ unsigned short f2bf(float f) {
  unsigned u = __builtin_bit_cast(unsigned, f);
  u = (u + 0x7FFFu + ((u >> 16) & 1u)) >> 16;
  return (unsigned short)u;
}
__device__ __forceinline__ float bf2f(unsigned short u) {
  return __builtin_bit_cast(float, (unsigned)u << 16);
}
__device__ __forceinline__ unsigned pk2(float a, float b) {
  return (unsigned)f2bf(a) | ((unsigned)f2bf(b) << 16);
}
__device__ __forceinline__ bf16x8 ld16(const void* p) {
  int4 v = *(const int4*)p;
  return __builtin_bit_cast(bf16x8, v);
}
__device__ __forceinline__ void gll16(const void* g, void* l) {
  __builtin_amdgcn_global_load_lds(
      (const __attribute__((address_space(1))) unsigned int*)g,
      (__attribute__((address_space(3))) unsigned int*)l, 16, 0, 0);
}

// =======================================================================
// TIER-1 PATH (ws >= 252 MB, proven on this harness)
// =======================================================================

// ---- prep: weights -> bf16, chunked pre-swizzled ----
__global__ void octa_prep2(const float* __restrict__ qkv_w, const float* __restrict__ proj_w,
                           unsigned short* __restrict__ wTq, unsigned short* __restrict__ pTq)
{
  int e = blockIdx.x * 256 + threadIdx.x;   // 262144
  if (e < 196608) {
    int c = e >> 13;                 // chunk id: nc*8 + kc
    int nc = c >> 3, kc = c & 7;
    int p2 = e & 8191;
    int n = p2 >> 5, cw = p2 & 31;
    int kl = cw ^ (((n >> 1) & 3) << 3);
    wTq[e] = f2bf(qkv_w[(size_t)(kc * 32 + kl) * 768 + nc * 256 + n]);
  } else {
    int e2 = e - 196608;
    int kc = e2 >> 13, p2 = e2 & 8191;
    int n = p2 >> 5, cw = p2 & 31;
    int kl = cw ^ (((n >> 1) & 3) << 3);
    pTq[e2] = f2bf(proj_w[(size_t)(kc * 32 + kl) * 256 + n]);
  }
}

// ---- data prep: f32 -> bf16, pre-swizzled per-chunk gll16 layout ----
__global__ __launch_bounds__(256)
void octa_dprep(const float* __restrict__ data, char* __restrict__ dbf)
{
  int e = blockIdx.x * 256 + threadIdx.x;       // [0, nbm*4096)
  int bm = e >> 12;
  int r = e & 4095;
  int t = r >> 9;
  int rr = r & 511;
  int row = rr >> 2, u = rr & 3;
  int l = u ^ ((row >> 1) & 3);
  const float* src = data + ((size_t)bm * 128 + row) * 256 + t * 32 + l * 8;
  float4 x = *(const float4*)src;
  float4 y = *(const float4*)(src + 4);
  int4 v;
  v.x = (int)pk2(x.x, x.y); v.y = (int)pk2(x.z, x.w);
  v.z = (int)pk2(y.x, y.y); v.w = (int)pk2(y.z, y.w);
  *(int4*)(dbf + (size_t)e * 16) = v;
}

// ---- kernel 1: qkv GEMM, all-gll16 dbuf, coalesced epilogue (R13-verified) ----
#define KQ_A0 0
#define KQ_A1 8192
#define KQ_B0 16384
#define KQ_B1 32768
#define KQ_LDS 49152

__global__ __launch_bounds__(512, 4)
void octa_qkv(const char* __restrict__ dbf, const float* __restrict__ qkv_b,
              const unsigned short* __restrict__ wTq, float* __restrict__ ws,
              char* __restrict__ qg, char* __restrict__ kg, char* __restrict__ vg)
{
  extern __shared__ char smem[];
  const int tid = threadIdx.x, lane = tid & 63, wid = tid >> 6;
  const int ql = lane & 15, lg = lane >> 4;
  const int bm = blockIdx.x / 3, nc = blockIdx.x - bm * 3;
  const int wr = wid >> 2, wc = wid & 3;
  const char* wbase = (const char*)wTq + (size_t)nc * 131072;
  const char* abase = dbf + (size_t)bm * 65536;

  // prologue: stage A0 + B0
  gll16(abase + wid * 1024 + lane * 16, smem + KQ_A0 + wid * 1024);
  gll16(wbase + wid * 1024 + lane * 16, smem + KQ_B0 + wid * 1024);
  gll16(wbase + 8192 + wid * 1024 + lane * 16, smem + KQ_B0 + 8192 + wid * 1024);
  __syncthreads();

  f32x4 acc[4][4];
  #pragma unroll
  for (int m = 0; m < 4; ++m)
    #pragma unroll
    for (int n = 0; n < 4; ++n) acc[m][n] = (f32x4){0.f, 0.f, 0.f, 0.f};

  #pragma unroll
  for (int t = 0; t < 8; ++t) {
    if (t < 7) {
      char* ab1 = smem + (((t + 1) & 1) ? KQ_A1 : KQ_A0);
      char* bb1 = smem + (((t + 1) & 1) ? KQ_B1 : KQ_B0);
      gll16(abase + (size_t)(t + 1) * 8192 + wid * 1024 + lane * 16, ab1 + wid * 1024);
      const char* bsrc = wbase + (size_t)(t + 1) * 16384;
      gll16(bsrc + wid * 1024 + lane * 16, bb1 + wid * 1024);
      gll16(bsrc + 8192 + wid * 1024 + lane * 16, bb1 + 8192 + wid * 1024);
    }
    const char* ab = smem + ((t & 1) ? KQ_A1 : KQ_A0);
    const char* bb = smem + ((t & 1) ? KQ_B1 : KQ_B0);
    bf16x8 af[4], bf[4];
    #pragma unroll
    for (int mt = 0; mt < 4; ++mt) {
      int row = wr * 64 + mt * 16 + ql;
      af[mt] = ld16(ab + row * 64 + ((lg * 16) ^ (((row >> 1) & 3) << 4)));
    }
    #pragma unroll
    for (int nt = 0; nt < 4; ++nt) {
      int n = wc * 64 + nt * 16 + ql;
      bf[nt] = ld16(bb + n * 64 + ((lg * 16) ^ (((n >> 1) & 3) << 4)));
    }
    #pragma unroll
    for (int nt = 0; nt < 4; ++nt)
      #pragma unroll
      for (int mt = 0; mt < 4; ++mt)
        acc[mt][nt] = __builtin_amdgcn_mfma_f32_16x16x32_bf16(af[mt], bf[nt], acc[mt][nt], 0, 0, 0);
    __syncthreads();
  }

  // bias values per nt (col fixed per thread)
  float bv[4];
  #pragma unroll
  for (int nt = 0; nt < 4; ++nt)
    bv[nt] = qkv_b[nc * 256 + wc * 64 + nt * 16 + ql];

  // std partials
  #pragma unroll
  for (int nt = 0; nt < 4; ++nt) {
    float s1 = 0.f, s2 = 0.f;
    #pragma unroll
    for (int mt = 0; mt < 4; ++mt)
      #pragma unroll
      for (int r = 0; r < 4; ++r) {
        float v = acc[mt][nt][r] + bv[nt];
        s1 += v; s2 += v * v;
      }
    s1 += __shfl_xor(s1, 16); s1 += __shfl_xor(s1, 32);
    s2 += __shfl_xor(s2, 16); s2 += __shfl_xor(s2, 32);
    if (lg == 0) {
      int col = wc * 64 + nt * 16 + ql;
      atomicAdd(ws + nc * 256 + col, s1);
      atomicAdd(ws + 768 + nc * 256 + col, s2);
    }
  }

  // coalesced store via LDS E[64][256] bf16 (32KB @0), two wr-halves
  char* base = nc == 0 ? qg : (nc == 1 ? kg : vg);
  const float cs = (nc == 0) ? SCALE_F : 1.0f;
  #pragma unroll
  for (int hh = 0; hh < 2; ++hh) {
    if (wr == hh) {
      #pragma unroll
      for (int nt = 0; nt < 4; ++nt) {
        int col = wc * 64 + nt * 16 + ql;
        #pragma unroll
        for (int mt = 0; mt < 4; ++mt)
          #pragma unroll
          for (int r = 0; r < 4; ++r) {
            int lrow = mt * 16 + lg * 4 + r;
            float v = (acc[mt][nt][r] + bv[nt]) * cs;
            *(unsigned short*)(smem + lrow * 512 + ((col * 2) ^ ((lrow & 7) << 4))) = f2bf(v);
          }
      }
    }
    __syncthreads();
    #pragma unroll
    for (int it = 0; it < 4; ++it) {
      int c = it * 512 + tid;             // [0,2048): lrow 64 x cu 32
      int lrow = c >> 5, cu = c & 31;
      int4 val = *(const int4*)(smem + lrow * 512 + ((cu * 16) ^ ((lrow & 7) << 4)));
      int gtok = bm * 128 + hh * 64 + lrow;
      int w = gtok / 40, tk = gtok - w * 40;
      int h = cu >> 2;
      *(int4*)(base + (size_t)(w * 8 + h) * 2560 + tk * 64 + (cu & 3) * 16) = val;
    }
    __syncthreads();
  }
}

// ---- fused attention+proj v4: bias transposed [h][qi][kj] -> 8B logits reads ----
// LDS 30720: BIAS [8 h][40 qi][80 B] @0 (25600, dead after logits) ;
//            P per-wave [48][80 B] x8 @0 (30720, after B2) ;
//            s_o [48][512 B] swz @0 (24576, after B3).
#define F3_LDS 30720

__global__ __launch_bounds__(512, 4)
void octa_attnproj3(const char* __restrict__ qg, const char* __restrict__ kg,
                    const char* __restrict__ vg, const float* __restrict__ maskp,
                    const int* __restrict__ rel_pos, const float* __restrict__ rpe_table,
                    const unsigned short* __restrict__ pTq, const float* __restrict__ proj_b,
                    float* __restrict__ out)
{
  extern __shared__ char smem[];
  const int tid = threadIdx.x, w = blockIdx.x, wid = tid >> 6;
  const int lane = tid & 63, ql = lane & 15, lg = lane >> 4, h = wid;
  const int perm = ql * 64 + lg * 16;
  const char* qb = qg + (size_t)(w * 8 + h) * 2560;
  const char* kb = kg + (size_t)(w * 8 + h) * 2560;
  const char* vb = vg + (size_t)(w * 8 + h) * 2560;

  // fragment loads issued up-front (latency hides under bias phase)
  bf16x8 kf0 = ld16(kb + perm), kf1 = ld16(kb + 1024 + perm), kf2 = ld16(kb + 2048 + perm);
  bf16x8 qf0 = ld16(qb + perm), qf1 = ld16(qb + 1024 + perm), qf2 = ld16(qb + 2048 + perm);
  // vT fragments via scalar gather from the L2-hot 2.5KB v slice ([tok][d] rows)
  union U8 { unsigned short u[8]; bf16x8 v; };
  U8 ua, ub, uc, ud;
  #pragma unroll
  for (int j = 0; j < 8; ++j) {
    int tok = lg * 8 + j;
    ua.u[j] = *(const unsigned short*)(vb + tok * 64 + ql * 2);
    ub.u[j] = *(const unsigned short*)(vb + tok * 64 + (16 + ql) * 2);
  }
  if (lg == 0) {
    #pragma unroll
    for (int j = 0; j < 8; ++j) {
      uc.u[j] = *(const unsigned short*)(vb + (32 + j) * 64 + ql * 2);
      ud.u[j] = *(const unsigned short*)(vb + (32 + j) * 64 + (16 + ql) * 2);
    }
  } else {
    #pragma unroll
    for (int j = 0; j < 8; ++j) { uc.u[j] = 0; ud.u[j] = 0; }
  }
  bf16x8 vA = ua.v, vB = ub.v, vC = uc.v, vD = ud.v;

  // phase 0: cooperative bias -> BIAS[h][qi][kj] bf16 (80B rows; rpe from global)
  for (int e = tid; e < 1600; e += 512) {
    int qi = e / 40, kj = e - qi * 40;
    float m = maskp[(size_t)w * 1600 + e];
    float b8[8];
    if (qi >= 8 && kj >= 8) {
      const int* rp = rel_pos + ((size_t)w * 1024 + (qi - 8) * 32 + (kj - 8)) * 3;
      int c0 = rp[0], c1 = rp[1], c2 = rp[2];
      c0 = min(25, max(-25, c0)); c1 = min(25, max(-25, c1)); c2 = min(25, max(-25, c2));
      const float4* r0 = (const float4*)(rpe_table + (c0 + 25) * 8);
      const float4* r1 = (const float4*)(rpe_table + (c1 + 76) * 8);
      const float4* r2 = (const float4*)(rpe_table + (c2 + 127) * 8);
      float4 a0 = r0[0], a1 = r1[0], a2 = r2[0];
      float4 b0 = r0[1], b1 = r1[1], b2 = r2[1];
      b8[0] = m + a0.x + a1.x + a2.x; b8[1] = m + a0.y + a1.y + a2.y;
      b8[2] = m + a0.z + a1.z + a2.z; b8[3] = m + a0.w + a1.w + a2.w;
      b8[4] = m + b0.x + b1.x + b2.x; b8[5] = m + b0.y + b1.y + b2.y;
      b8[6] = m + b0.z + b1.z + b2.z; b8[7] = m + b0.w + b1.w + b2.w;
    } else {
      #pragma unroll
      for (int hh = 0; hh < 8; ++hh) b8[hh] = m;
    }
    #pragma unroll
    for (int hh = 0; hh < 8; ++hh)
      *(unsigned short*)(smem + hh * 3200 + qi * 80 + kj * 2) = f2bf(b8[hh]);
  }

  // QK^T (register-only): ST[kj][qi] = mfma(A=k, B=q)
  f32x4 st[9];
  {
    bf16x8 kf[3] = {kf0, kf1, kf2}, qf[3] = {qf0, qf1, qf2};
    __builtin_amdgcn_s_setprio(1);
    #pragma unroll
    for (int a = 0; a < 3; ++a)
      #pragma unroll
      for (int b = 0; b < 3; ++b)
        st[a * 3 + b] = __builtin_amdgcn_mfma_f32_16x16x32_bf16(
            kf[a], qf[b], (f32x4){0.f, 0.f, 0.f, 0.f}, 0, 0, 0);
    __builtin_amdgcn_s_setprio(0);
  }
  __syncthreads();   // B1: bias visible

  // logits: one 8B LDS read covers 4 consecutive kj (r=0..3)
  const char* bb_ = smem + h * 3200;
  float mx[3] = {-3e38f, -3e38f, -3e38f};
  #pragma unroll
  for (int a = 0; a < 3; ++a) {
    #pragma unroll
    for (int b = 0; b < 3; ++b) {
      int kj0 = a * 16 + lg * 4;
      int qi = b * 16 + ql;
      unsigned bx = 0, by = 0;
      if (kj0 < 40 && qi < 40) {
        uint2 t = *(const uint2*)(bb_ + qi * 80 + kj0 * 2);
        bx = t.x; by = t.y;
      }
      unsigned short bv4[4] = {
        (unsigned short)(bx & 0xFFFFu), (unsigned short)(bx >> 16),
        (unsigned short)(by & 0xFFFFu), (unsigned short)(by >> 16)
      };
      #pragma unroll
      for (int r = 0; r < 4; ++r) {
        int kj = kj0 + r;
        float s = st[a * 3 + b][r];
        if (kj < 40) {
          if (qi < 40) s += bf2f(bv4[r]);
        } else {
          s = -1e30f;
        }
        st[a * 3 + b][r] = s;
        mx[b] = fmaxf(mx[b], s);
      }
    }
  }
  __syncthreads();   // B2: bias reads done -> P region writable

  #pragma unroll
  for (int b = 0; b < 3; ++b) {
    mx[b] = fmaxf(mx[b], __shfl_xor(mx[b], 16));
    mx[b] = fmaxf(mx[b], __shfl_xor(mx[b], 32));
  }
  float sum[3] = {0.f, 0.f, 0.f};
  #pragma unroll
  for (int a = 0; a < 3; ++a)
    #pragma unroll
    for (int b = 0; b < 3; ++b)
      #pragma unroll
      for (int r = 0; r < 4; ++r) {
        float e = __expf(st[a * 3 + b][r] - mx[b]);
        st[a * 3 + b][r] = e;
        sum[b] += e;
      }
  float inv[3];
  #pragma unroll
  for (int b = 0; b < 3; ++b) {
    sum[b] += __shfl_xor(sum[b], 16);
    sum[b] += __shfl_xor(sum[b], 32);
    inv[b] = 1.f / sum[b];
  }

  // PV in two kj-halves; per-wave P buffer @ wid*3840, 80B rows
  char* pb_ = smem + wid * 3840;
  f32x4 ot[6];
  #pragma unroll
  for (int i = 0; i < 6; ++i) ot[i] = (f32x4){0.f, 0.f, 0.f, 0.f};

  #pragma unroll
  for (int a = 0; a < 2; ++a)
    #pragma unroll
    for (int b = 0; b < 3; ++b)
      #pragma unroll
      for (int r = 0; r < 4; ++r) {
        int kj = a * 16 + lg * 4 + r, qi = b * 16 + ql;
        *(unsigned short*)(pb_ + qi * 80 + kj * 2) = f2bf(st[a * 3 + b][r] * inv[b]);
      }
  asm volatile("" ::: "memory");
  __builtin_amdgcn_s_setprio(1);
  #pragma unroll
  for (int b = 0; b < 3; ++b) {
    bf16x8 pf = ld16(pb_ + (b * 16 + ql) * 80 + lg * 16);
    ot[b]     = __builtin_amdgcn_mfma_f32_16x16x32_bf16(vA, pf, ot[b], 0, 0, 0);
    ot[3 + b] = __builtin_amdgcn_mfma_f32_16x16x32_bf16(vB, pf, ot[3 + b], 0, 0, 0);
  }
  __builtin_amdgcn_s_setprio(0);
  asm volatile("" ::: "memory");
  #pragma unroll
  for (int b = 0; b < 3; ++b) {
    int qi = b * 16 + ql;
    #pragma unroll
    for (int r = 0; r < 4; ++r)
      *(unsigned short*)(pb_ + qi * 80 + (lg * 4 + r) * 2) = f2bf(st[6 + b][r] * inv[b]);
    *(uint2*)(pb_ + qi * 80 + 32 + lg * 8) = make_uint2(0u, 0u);
  }
  asm volatile("" ::: "memory");
  __builtin_amdgcn_s_setprio(1);
  #pragma unroll
  for (int b = 0; b < 3; ++b) {
    bf16x8 pf = ld16(pb_ + (b * 16 + ql) * 80 + lg * 16);
    ot[b]     = __builtin_amdgcn_mfma_f32_16x16x32_bf16(vC, pf, ot[b], 0, 0, 0);
    ot[3 + b] = __builtin_amdgcn_mfma_f32_16x16x32_bf16(vD, pf, ot[3 + b], 0, 0, 0);
  }
  __builtin_amdgcn_s_setprio(0);

  __syncthreads();   // B3: P dead
  #pragma unroll
  for (int dm = 0; dm < 2; ++dm)
    #pragma unroll
    for (int b = 0; b < 3; ++b) {
      int qi = b * 16 + ql;
      unsigned u0 = pk2(ot[dm * 3 + b][0], ot[dm * 3 + b][1]);
      unsigned u1 = pk2(ot[dm * 3 + b][2], ot[dm * 3 + b][3]);
      int colb = (h * 32 + dm * 16 + lg * 4) * 2;
      *(uint2*)(smem + qi * 512 + (colb ^ ((qi & 7) << 4))) = make_uint2(u0, u1);
    }
  __syncthreads();   // B4: s_o visible

  f32x4 pacc[3][2];
  #pragma unroll
  for (int m = 0; m < 3; ++m)
    #pragma unroll
    for (int n = 0; n < 2; ++n) pacc[m][n] = (f32x4){0.f, 0.f, 0.f, 0.f};
  const int c0 = wid * 32;
  const char* pB = (const char*)pTq;

  #pragma unroll
  for (int t = 0; t < 8; ++t) {
    bf16x8 af[3], bfr[2];
    #pragma unroll
    for (int mt = 0; mt < 3; ++mt) {
      int row = mt * 16 + ql;
      af[mt] = ld16(smem + row * 512 + ((t * 64 + lg * 16) ^ ((row & 7) << 4)));
    }
    #pragma unroll
    for (int nt = 0; nt < 2; ++nt) {
      int n = c0 + nt * 16 + ql;
      bfr[nt] = ld16(pB + (size_t)t * 16384 + n * 64 + ((lg * 16) ^ (((n >> 1) & 3) << 4)));
    }
    __builtin_amdgcn_s_setprio(1);
    #pragma unroll
    for (int nt = 0; nt < 2; ++nt)
      #pragma unroll
      for (int mt = 0; mt < 3; ++mt)
        pacc[mt][nt] = __builtin_amdgcn_mfma_f32_16x16x32_bf16(af[mt], bfr[nt], pacc[mt][nt], 0, 0, 0);
    __builtin_amdgcn_s_setprio(0);
  }

  #pragma unroll
  for (int nt = 0; nt < 2; ++nt) {
    int col = c0 + nt * 16 + ql;
    float pb = proj_b[col];
    #pragma unroll
    for (int mt = 0; mt < 3; ++mt)
      #pragma unroll
      for (int r = 0; r < 4; ++r) {
        int row = mt * 16 + lg * 4 + r;
        if (row < 40)
          out[(size_t)(w * 40 + row) * 256 + col] = pacc[mt][nt][r] + pb;
      }
  }
}

// ---- std finalize (all paths) ----
__global__ void octa_std(const float* __restrict__ ws, float* __restrict__ out,
                         int total_rows, size_t off)
{
  int j = blockIdx.x * 256 + threadIdx.x;
  if (j < 768) {
    float s = ws[j], ss = ws[768 + j];
    float T = (float)total_rows;
    float var = (ss - s * s / T) / (T - 1.f);
    out[off + j] = sqrtf(fmaxf(var, 0.f));
  }
}

// =======================================================================
// FALLBACK PATH: round-4 fused kernel (verified), used if ws too small
// =======================================================================
#define O_RPE 0
#define O_MSK 4896
#define O_IDX 8096
#define O_A   12192
#define O_ATT 36768
#define B1_SZ 49152
#define ATT_STRIDE 11776
#define AK 3840
#define AV 7680
#define B2_S (O_ATT + 94208)
#define B2_A O_ATT
#define LDS_BYTES_V4 163744

__device__ __forceinline__ int a_addr(int row, int byte) {
  return O_A + row * 512 + (byte ^ ((row & 7) << 4));
}
__device__ __forceinline__ int v_addr(int d, int byte) {
  return AV + d * 128 + (byte ^ ((d & 7) << 4));
}

__global__ void octa_prep_v4(const float* __restrict__ qkv_w, const float* __restrict__ proj_w,
                             unsigned short* __restrict__ wTq, unsigned short* __restrict__ pTq)
{
  int idx = blockIdx.x * 256 + threadIdx.x;
  if (idx < 196608) {
    int n = idx >> 8, k = idx & 255;
    wTq[idx] = f2bf(qkv_w[k * 768 + n]);
  } else {
    int i = idx - 196608;
    int n = i >> 8, k = i & 255;
    pTq[i] = f2bf(proj_w[k * 256 + n]);
  }
}

__global__ __launch_bounds__(512, 2)
void octa_main_v4(const float* __restrict__ data, const int* __restrict__ rel_pos,
                  const float* __restrict__ maskp, const float* __restrict__ qkv_b,
                  const float* __restrict__ proj_b, const float* __restrict__ rpe_table,
                  const unsigned short* __restrict__ wTq, const unsigned short* __restrict__ pTq,
                  float* __restrict__ ws, float* __restrict__ out)
{
  extern __shared__ char smem[];
  float* s_rpe = (float*)(smem + O_RPE);
  const int tid = threadIdx.x;
  const int w   = blockIdx.x;
  const int wid = tid >> 6;
  const int lane = tid & 63;
  const int ql = lane & 15;
  const int lg = lane >> 4;
  const int h  = wid;
  const int ab = O_ATT + wid * ATT_STRIDE;

  {
    #pragma unroll
    for (int it = 0; it < 6; ++it) {
      int g = it * 512 + tid;
      int n = g >> 2, slot = g & 3;
      const char* src = (const char*)wTq + (size_t)n * 512 + ((slot * 16) ^ ((n & 3) << 4));
      gll16(src, smem + O_ATT + it * 8192 + wid * 1024);
    }
  }
  for (int f = tid; f < 1224; f += 512) s_rpe[f] = rpe_table[f];
  for (int f = tid; f < 400; f += 512) {
    float4 m4 = ((const float4*)(maskp + (size_t)w * 1600))[f];
    uint2 pk;
    pk.x = pk2(m4.x, m4.y); pk.y = pk2(m4.z, m4.w);
    *(uint2*)(smem + O_MSK + f * 8) = pk;
  }
  for (int p = tid; p < 1024; p += 512) {
    const int* rp = rel_pos + ((size_t)w * 1024 + p) * 3;
    int c0 = rp[0], c1 = rp[1], c2 = rp[2];
    c0 = min(25, max(-25, c0)); c1 = min(25, max(-25, c1)); c2 = min(25, max(-25, c2));
    unsigned pk = (unsigned)(c0 + 25) | ((unsigned)(c1 + 76) << 10) | ((unsigned)(c2 + 127) << 20);
    *(unsigned*)(smem + O_IDX + ((p * 4) ^ (((p >> 5) & 7) << 4))) = pk;
  }
  {
    const float4* src = (const float4*)(data + (size_t)w * 10240);
    for (int f = tid; f < 2560; f += 512) {
      int token = f >> 6, q4 = f & 63;
      float4 d4 = src[f];
      uint2 pk;
      pk.x = pk2(d4.x, d4.y); pk.y = pk2(d4.z, d4.w);
      *(uint2*)(smem + a_addr(token, q4 * 8)) = pk;
    }
    int token = 40 + (tid >> 6), byte = (tid & 63) * 8;
    *(uint2*)(smem + a_addr(token, byte)) = make_uint2(0u, 0u);
  }
  __syncthreads();

  f32x4 acc[18];
  #pragma unroll
  for (int i = 0; i < 18; ++i) acc[i] = (f32x4){0.f, 0.f, 0.f, 0.f};

  for (int t = 0; t < 8; ++t) {
    if (t < 7) {
      int bb = O_ATT + ((t + 1) & 1) * B1_SZ;
      #pragma unroll
      for (int it = 0; it < 6; ++it) {
        int g = it * 512 + tid;
        int n = g >> 2, slot = g & 3;
        const char* src = (const char*)wTq + (size_t)n * 512 + (t + 1) * 64
                          + ((slot * 16) ^ ((n & 3) << 4));
        gll16(src, smem + bb + it * 8192 + wid * 1024);
      }
    }
    const int bb = O_ATT + (t & 1) * B1_SZ;
    bf16x8 af[3];
    #pragma unroll
    for (int mt = 0; mt < 3; ++mt)
      af[mt] = ld16(smem + a_addr(mt * 16 + ql, t * 64 + lg * 16));
    #pragma unroll
    for (int j = 0; j < 6; ++j) {
      int n = ((j >> 1) * 16 + 2 * wid + (j & 1)) * 16 + ql;
      bf16x8 bf = ld16(smem + bb + n * 64 + ((lg * 16) ^ ((n & 3) << 4)));
      #pragma unroll
      for (int mt = 0; mt < 3; ++mt)
        acc[j * 3 + mt] = __builtin_amdgcn_mfma_f32_16x16x32_bf16(af[mt], bf, acc[j * 3 + mt], 0, 0, 0);
    }
    __syncthreads();
  }

  {
    #pragma unroll
    for (int it = 0; it < 4; ++it) {
      int g = it * 512 + tid;
      int n = g >> 3, slot = g & 7;
      const char* src = (const char*)pTq + (size_t)n * 512 + ((slot * 16) ^ ((n & 7) << 4));
      gll16(src, smem + B2_S + it * 8192 + wid * 1024);
    }
  }

  #pragma unroll
  for (int j = 0; j < 6; ++j) {
    int sec = j >> 1;
    int ncol = sec * 256 + 32 * wid + (j & 1) * 16 + ql;
    int d = (j & 1) * 16 + ql;
    float bias = qkv_b[ncol];
    float s1 = 0.f, s2 = 0.f;
    #pragma unroll
    for (int mt = 0; mt < 3; ++mt) {
      #pragma unroll
      for (int r = 0; r < 4; ++r) {
        int token = mt * 16 + lg * 4 + r;
        float v = acc[j * 3 + mt][r] + bias;
        if (token < 40) { s1 += v; s2 += v * v; }
        if (sec == 0)
          *(unsigned short*)(smem + ab + token * 80 + d * 2) = f2bf(v * SCALE_F);
        else if (sec == 1)
          *(unsigned short*)(smem + ab + AK + token * 80 + d * 2) = f2bf(v);
        else
          *(unsigned short*)(smem + ab + v_addr(d, token * 2)) = f2bf(v);
      }
    }
    s1 += __shfl_xor(s1, 16); s1 += __shfl_xor(s1, 32);
    s2 += __shfl_xor(s2, 16); s2 += __shfl_xor(s2, 32);
    if (lg == 0) { atomicAdd(ws + ncol, s1); atomicAdd(ws + 768 + ncol, s2); }
  }
  {
    int zd = lane >> 1;
    int zb = 96 + (lane & 1) * 16;
    *(int4*)(smem + ab + v_addr(zd, zb)) = (int4){0, 0, 0, 0};
  }
  asm volatile("" ::: "memory");

  f32x4 st[9];
  {
    bf16x8 kf[3], qf[3];
    #pragma unroll
    for (int a = 0; a < 3; ++a) kf[a] = ld16(smem + ab + AK + (a * 16 + ql) * 80 + lg * 16);
    #pragma unroll
    for (int b = 0; b < 3; ++b) qf[b] = ld16(smem + ab + (b * 16 + ql) * 80 + lg * 16);
    #pragma unroll
    for (int a = 0; a < 3; ++a)
      #pragma unroll
      for (int b = 0; b < 3; ++b)
        st[a * 3 + b] = __builtin_amdgcn_mfma_f32_16x16x32_bf16(
            kf[a], qf[b], (f32x4){0.f, 0.f, 0.f, 0.f}, 0, 0, 0);
  }

  float mx[3] = {-3e38f, -3e38f, -3e38f};
  #pragma unroll
  for (int a = 0; a < 3; ++a) {
    #pragma unroll
    for (int b = 0; b < 3; ++b) {
      #pragma unroll
      for (int r = 0; r < 4; ++r) {
        int kj = a * 16 + lg * 4 + r;
        int qi = b * 16 + ql;
        float s = st[a * 3 + b][r];
        if (kj < 40) {
          if (qi < 40) {
            s += bf2f(*(const unsigned short*)(smem + O_MSK + (qi * 40 + kj) * 2));
            if (kj >= 8 && qi >= 8) {
              int p = (qi - 8) * 32 + (kj - 8);
              unsigned pk = *(const unsigned*)(smem + O_IDX + ((p * 4) ^ (((p >> 5) & 7) << 4)));
              s += s_rpe[(pk & 1023) * 8 + h] + s_rpe[((pk >> 10) & 1023) * 8 + h]
                 + s_rpe[(pk >> 20) * 8 + h];
            }
          }
        } else {
          s = -1e30f;
        }
        st[a * 3 + b][r] = s;
        mx[b] = fmaxf(mx[b], s);
      }
    }
  }
  #pragma unroll
  for (int b = 0; b < 3; ++b) {
    mx[b] = fmaxf(mx[b], __shfl_xor(mx[b], 16));
    mx[b] = fmaxf(mx[b], __shfl_xor(mx[b], 32));
  }
  float sum[3] = {0.f, 0.f, 0.f};
  #pragma unroll
  for (int a = 0; a < 3; ++a)
    #pragma unroll
    for (int b = 0; b < 3; ++b)
      #pragma unroll
      for (int r = 0; r < 4; ++r) {
        float e = __expf(st[a * 3 + b][r] - mx[b]);
        st[a * 3 + b][r] = e;
        sum[b] += e;
      }
  float inv[3];
  #pragma unroll
  for (int b = 0; b < 3; ++b) {
    sum[b] += __shfl_xor(sum[b], 16);
    sum[b] += __shfl_xor(sum[b], 32);
    inv[b] = 1.f / sum[b];
  }

  f32x4 ot[6];
  #pragma unroll
  for (int i = 0; i < 6; ++i) ot[i] = (f32x4){0.f, 0.f, 0.f, 0.f};

  #pragma unroll
  for (int a = 0; a < 2; ++a)
    #pragma unroll
    for (int b = 0; b < 3; ++b)
      #pragma unroll
      for (int r = 0; r < 4; ++r) {
        int kj = a * 16 + lg * 4 + r, qi = b * 16 + ql;
        *(unsigned short*)(smem + ab + qi * 80 + kj * 2) = f2bf(st[a * 3 + b][r] * inv[b]);
      }
  asm volatile("" ::: "memory");
  {
    bf16x8 vf0 = ld16(smem + ab + v_addr(ql, lg * 16));
    bf16x8 vf1 = ld16(smem + ab + v_addr(16 + ql, lg * 16));
    #pragma unroll
    for (int b = 0; b < 3; ++b) {
      bf16x8 pf = ld16(smem + ab + (b * 16 + ql) * 80 + lg * 16);
      ot[b] = __builtin_amdgcn_mfma_f32_16x16x32_bf16(vf0, pf, ot[b], 0, 0, 0);
      ot[3 + b] = __builtin_amdgcn_mfma_f32_16x16x32_bf16(vf1, pf, ot[3 + b], 0, 0, 0);
    }
  }
  asm volatile("" ::: "memory");
  #pragma unroll
  for (int b = 0; b < 3; ++b) {
    int qi = b * 16 + ql;
    #pragma unroll
    for (int r = 0; r < 4; ++r) {
      int kj = 32 + lg * 4 + r;
      *(unsigned short*)(smem + ab + qi * 80 + (kj - 32) * 2) = f2bf(st[6 + b][r] * inv[b]);
    }
    *(uint2*)(smem + ab + qi * 80 + 32 + lg * 8) = make_uint2(0u, 0u);
  }
  asm volatile("" ::: "memory");
  {
    bf16x8 vf0 = ld16(smem + ab + v_addr(ql, 64 + lg * 16));
    bf16x8 vf1 = ld16(smem + ab + v_addr(16 + ql, 64 + lg * 16));
    #pragma unroll
    for (int b = 0; b < 3; ++b) {
      bf16x8 pf = ld16(smem + ab + (b * 16 + ql) * 80 + lg * 16);
      ot[b] = __builtin_amdgcn_mfma_f32_16x16x32_bf16(vf0, pf, ot[b], 0, 0, 0);
      ot[3 + b] = __builtin_amdgcn_mfma_f32_16x16x32_bf16(vf1, pf, ot[3 + b], 0, 0, 0);
    }
  }
  #pragma unroll
  for (int dm = 0; dm < 2; ++dm)
    #pragma unroll
    for (int b = 0; b < 3; ++b)
      #pragma unroll
      for (int r = 0; r < 4; ++r) {
        int d = dm * 16 + lg * 4 + r;
        int qi = b * 16 + ql;
        *(unsigned short*)(smem + a_addr(qi, (h * 32 + d) * 2)) = f2bf(ot[dm * 3 + b][r]);
      }
  __syncthreads();

  f32x4 oacc[6];
  #pragma unroll
  for (int i = 0; i < 6; ++i) oacc[i] = (f32x4){0.f, 0.f, 0.f, 0.f};

  for (int t = 0; t < 4; ++t) {
    if (t < 3) {
      int bb = ((t + 1) & 1) ? B2_A : B2_S;
      #pragma unroll
      for (int it = 0; it < 4; ++it) {
        int g = it * 512 + tid;
        int n = g >> 3, slot = g & 7;
        const char* src = (const char*)pTq + (size_t)n * 512 + (t + 1) * 128
                          + ((slot * 16) ^ ((n & 7) << 4));
        gll16(src, smem + bb + it * 8192 + wid * 1024);
      }
    }
    const int bb = (t & 1) ? B2_A : B2_S;
    #pragma unroll
    for (int ks = 0; ks < 2; ++ks) {
      bf16x8 af[3];
      #pragma unroll
      for (int mt = 0; mt < 3; ++mt)
        af[mt] = ld16(smem + a_addr(mt * 16 + ql, t * 128 + ks * 64 + lg * 16));
      #pragma unroll
      for (int nt = 0; nt < 2; ++nt) {
        int n = (2 * wid + nt) * 16 + ql;
        bf16x8 bf = ld16(smem + bb + n * 128 + ((ks * 64 + lg * 16) ^ ((n & 7) << 4)));
        #pragma unroll
        for (int mt = 0; mt < 3; ++mt)
          oacc[nt * 3 + mt] = __builtin_amdgcn_mfma_f32_16x16x32_bf16(af[mt], bf, oacc[nt * 3 + mt], 0, 0, 0);
      }
    }
    __syncthreads();
  }

  #pragma unroll
  for (int nt = 0; nt < 2; ++nt) {
    int ncol = (2 * wid + nt) * 16 + ql;
    float pb = proj_b[ncol];
    #pragma unroll
    for (int mt = 0; mt < 3; ++mt)
      #pragma unroll
      for (int r = 0; r < 4; ++r) {
        int token = mt * 16 + lg * 4 + r;
        if (token < 40)
          out[(size_t)w * 10240 + token * 256 + ncol] = oacc[nt * 3 + mt][r] + pb;
      }
  }
}

// =======================================================================
extern "C" void kernel_launch(void* const* d_in, const int* in_sizes, int n_in,
                              void* d_out, int out_size, void* d_ws, size_t ws_size,
                              hipStream_t stream) {
  const float* data    = (const float*)d_in[0];
  const int*   rel_pos = (const int*)d_in[1];
  const float* maskp   = (const float*)d_in[2];
  const float* qkv_w   = (const float*)d_in[3];
  const float* qkv_b   = (const float*)d_in[4];
  const float* proj_w  = (const float*)d_in[5];
  const float* proj_b  = (const float*)d_in[6];
  const float* rpe_tab = (const float*)d_in[7];
  float* out = (float*)d_out;
  float* ws  = (float*)d_ws;

  const int nw = in_sizes[1] / 3072;           // 4096
  const int total_rows = nw * 40;
  const size_t std_off = (size_t)nw * 10240;
  const size_t SZ = 83886080ull;               // one q/k/v tensor, bf16
  const int nbm = nw * 40 / 128;               // 1280

  const size_t WS1 = 530432ull + 3ull * SZ + 4096ull;

  unsigned short* wTq = (unsigned short*)((char*)d_ws + 6144);
  unsigned short* pTq = (unsigned short*)((char*)d_ws + 399360);

  hipMemsetAsync(ws, 0, 6144, stream);

  if (ws_size >= WS1) {
    char* qg = (char*)d_ws + 530432;
    char* kg = qg + SZ;
    char* vg = kg + SZ;
    char* dbf = (char*)d_out;                  // 84 MB staging: dead after qkv,
                                               // overwritten by attnproj3's out-write
    (void)hipFuncSetAttribute((const void*)octa_attnproj3,
                              hipFuncAttributeMaxDynamicSharedMemorySize, F3_LDS);
    hipLaunchKernelGGL(octa_prep2, dim3(1024), dim3(256), 0, stream, qkv_w, proj_w, wTq, pTq);
    hipLaunchKernelGGL(octa_dprep, dim3(nbm * 16), dim3(256), 0, stream, data, dbf);
    hipLaunchKernelGGL(octa_qkv, dim3(nbm * 3), dim3(512), KQ_LDS, stream,
                       dbf, qkv_b, wTq, ws, qg, kg, vg);
    hipLaunchKernelGGL(octa_attnproj3, dim3(nw), dim3(512), F3_LDS, stream,
                       qg, kg, vg, maskp, rel_pos, rpe_tab, pTq, proj_b, out);
    hipLaunchKernelGGL(octa_std, dim3(3), dim3(256), 0, stream, ws, out, total_rows, std_off);
  } else {
    hipLaunchKernelGGL(octa_prep_v4, dim3(1024), dim3(256), 0, stream, qkv_w, proj_w, wTq, pTq);
    (void)hipFuncSetAttribute((const void*)octa_main_v4,
                              hipFuncAttributeMaxDynamicSharedMemorySize, LDS_BYTES_V4);
    hipLaunchKernelGGL(octa_main_v4, dim3(nw), dim3(512), LDS_BYTES_V4, stream,
                       data, rel_pos, maskp, qkv_b, proj_b, rpe_tab, wTq, pTq, ws, out);
    hipLaunchKernelGGL(octa_std, dim3(3), dim3(256), 0, stream, ws, out, total_rows, std_off);
  }
}

// Round 17
// 351.418 us; speedup vs baseline: 1.8019x; 1.0042x over previous
//
#include <hip/hip_runtime.h>
#include <math.h>

// OctreeAttention: C=256, H=8, HD=32, K=32, G=8, W=40, NW=4096, RPE rows=153
#define SCALE_F 0.17677669529663687f  // 32^-0.5

typedef __bf16 bf16x8 __attribute__((ext_vector_type(8)));
typedef float f32x4 __attribute__((ext_vector_type(4)));

__device__ __forceinline__ unsigned short f2bf(float f) {
  unsigned u = __builtin_bit_cast(unsigned, f);
  u = (u + 0x7FFFu + ((u >> 16) & 1u)) >> 16;
  return (unsigned short)u;
}
__device__ __forceinline__ float bf2f(unsigned short u) {
  return __builtin_bit_cast(float, (unsigned)u << 16);
}
__device__ __forceinline__ unsigned pk2(float a, float b) {
  return (unsigned)f2bf(a) | ((unsigned)f2bf(b) << 16);
}
__device__ __forceinline__ bf16x8 ld16(const void* p) {
  int4 v = *(const int4*)p;
  return __builtin_bit_cast(bf16x8, v);
}
__device__ __forceinline__ void gll16(const void* g, void* l) {
  __builtin_amdgcn_global_load_lds(
      (const __attribute__((address_space(1))) unsigned int*)g,
      (__attribute__((address_space(3))) unsigned int*)l, 16, 0, 0);
}

// =======================================================================
// TIER-1 PATH (ws >= 252 MB, proven on this harness)
// =======================================================================

// ---- prep: weights -> bf16, chunked pre-swizzled ----
__global__ void octa_prep2(const float* __restrict__ qkv_w, const float* __restrict__ proj_w,
                           unsigned short* __restrict__ wTq, unsigned short* __restrict__ pTq)
{
  int e = blockIdx.x * 256 + threadIdx.x;   // 262144
  if (e < 196608) {
    int c = e >> 13;                 // chunk id: nc*8 + kc
    int nc = c >> 3, kc = c & 7;
    int p2 = e & 8191;
    int n = p2 >> 5, cw = p2 & 31;
    int kl = cw ^ (((n >> 1) & 3) << 3);
    wTq[e] = f2bf(qkv_w[(size_t)(kc * 32 + kl) * 768 + nc * 256 + n]);
  } else {
    int e2 = e - 196608;
    int kc = e2 >> 13, p2 = e2 & 8191;
    int n = p2 >> 5, cw = p2 & 31;
    int kl = cw ^ (((n >> 1) & 3) << 3);
    pTq[e2] = f2bf(proj_w[(size_t)(kc * 32 + kl) * 256 + n]);
  }
}

// ---- data prep: f32 -> bf16, pre-swizzled per-chunk gll16 layout ----
__global__ __launch_bounds__(256)
void octa_dprep(const float* __restrict__ data, char* __restrict__ dbf)
{
  int e = blockIdx.x * 256 + threadIdx.x;       // [0, nbm*4096)
  int bm = e >> 12;
  int r = e & 4095;
  int t = r >> 9;
  int rr = r & 511;
  int row = rr >> 2, u = rr & 3;
  int l = u ^ ((row >> 1) & 3);
  const float* src = data + ((size_t)bm * 128 + row) * 256 + t * 32 + l * 8;
  float4 x = *(const float4*)src;
  float4 y = *(const float4*)(src + 4);
  int4 v;
  v.x = (int)pk2(x.x, x.y); v.y = (int)pk2(x.z, x.w);
  v.z = (int)pk2(y.x, y.y); v.w = (int)pk2(y.z, y.w);
  *(int4*)(dbf + (size_t)e * 16) = v;
}

// ---- kernel 1: qkv GEMM, all-gll16 dbuf, coalesced epilogue (R13-verified) ----
#define KQ_A0 0
#define KQ_A1 8192
#define KQ_B0 16384
#define KQ_B1 32768
#define KQ_LDS 49152

__global__ __launch_bounds__(512, 4)
void octa_qkv(const char* __restrict__ dbf, const float* __restrict__ qkv_b,
              const unsigned short* __restrict__ wTq, float* __restrict__ ws,
              char* __restrict__ qg, char* __restrict__ kg, char* __restrict__ vg)
{
  extern __shared__ char smem[];
  const int tid = threadIdx.x, lane = tid & 63, wid = tid >> 6;
  const int ql = lane & 15, lg = lane >> 4;
  const int bm = blockIdx.x / 3, nc = blockIdx.x - bm * 3;
  const int wr = wid >> 2, wc = wid & 3;
  const char* wbase = (const char*)wTq + (size_t)nc * 131072;
  const char* abase = dbf + (size_t)bm * 65536;

  // prologue: stage A0 + B0
  gll16(abase + wid * 1024 + lane * 16, smem + KQ_A0 + wid * 1024);
  gll16(wbase + wid * 1024 + lane * 16, smem + KQ_B0 + wid * 1024);
  gll16(wbase + 8192 + wid * 1024 + lane * 16, smem + KQ_B0 + 8192 + wid * 1024);
  __syncthreads();

  f32x4 acc[4][4];
  #pragma unroll
  for (int m = 0; m < 4; ++m)
    #pragma unroll
    for (int n = 0; n < 4; ++n) acc[m][n] = (f32x4){0.f, 0.f, 0.f, 0.f};

  #pragma unroll
  for (int t = 0; t < 8; ++t) {
    if (t < 7) {
      char* ab1 = smem + (((t + 1) & 1) ? KQ_A1 : KQ_A0);
      char* bb1 = smem + (((t + 1) & 1) ? KQ_B1 : KQ_B0);
      gll16(abase + (size_t)(t + 1) * 8192 + wid * 1024 + lane * 16, ab1 + wid * 1024);
      const char* bsrc = wbase + (size_t)(t + 1) * 16384;
      gll16(bsrc + wid * 1024 + lane * 16, bb1 + wid * 1024);
      gll16(bsrc + 8192 + wid * 1024 + lane * 16, bb1 + 8192 + wid * 1024);
    }
    const char* ab = smem + ((t & 1) ? KQ_A1 : KQ_A0);
    const char* bb = smem + ((t & 1) ? KQ_B1 : KQ_B0);
    bf16x8 af[4], bf[4];
    #pragma unroll
    for (int mt = 0; mt < 4; ++mt) {
      int row = wr * 64 + mt * 16 + ql;
      af[mt] = ld16(ab + row * 64 + ((lg * 16) ^ (((row >> 1) & 3) << 4)));
    }
    #pragma unroll
    for (int nt = 0; nt < 4; ++nt) {
      int n = wc * 64 + nt * 16 + ql;
      bf[nt] = ld16(bb + n * 64 + ((lg * 16) ^ (((n >> 1) & 3) << 4)));
    }
    #pragma unroll
    for (int nt = 0; nt < 4; ++nt)
      #pragma unroll
      for (int mt = 0; mt < 4; ++mt)
        acc[mt][nt] = __builtin_amdgcn_mfma_f32_16x16x32_bf16(af[mt], bf[nt], acc[mt][nt], 0, 0, 0);
    __syncthreads();
  }

  // bias values per nt (col fixed per thread)
  float bv[4];
  #pragma unroll
  for (int nt = 0; nt < 4; ++nt)
    bv[nt] = qkv_b[nc * 256 + wc * 64 + nt * 16 + ql];

  // std partials
  #pragma unroll
  for (int nt = 0; nt < 4; ++nt) {
    float s1 = 0.f, s2 = 0.f;
    #pragma unroll
    for (int mt = 0; mt < 4; ++mt)
      #pragma unroll
      for (int r = 0; r < 4; ++r) {
        float v = acc[mt][nt][r] + bv[nt];
        s1 += v; s2 += v * v;
      }
    s1 += __shfl_xor(s1, 16); s1 += __shfl_xor(s1, 32);
    s2 += __shfl_xor(s2, 16); s2 += __shfl_xor(s2, 32);
    if (lg == 0) {
      int col = wc * 64 + nt * 16 + ql;
      atomicAdd(ws + nc * 256 + col, s1);
      atomicAdd(ws + 768 + nc * 256 + col, s2);
    }
  }

  // coalesced store via LDS E[64][256] bf16 (32KB @0), two wr-halves
  char* base = nc == 0 ? qg : (nc == 1 ? kg : vg);
  const float cs = (nc == 0) ? SCALE_F : 1.0f;
  #pragma unroll
  for (int hh = 0; hh < 2; ++hh) {
    if (wr == hh) {
      #pragma unroll
      for (int nt = 0; nt < 4; ++nt) {
        int col = wc * 64 + nt * 16 + ql;
        #pragma unroll
        for (int mt = 0; mt < 4; ++mt)
          #pragma unroll
          for (int r = 0; r < 4; ++r) {
            int lrow = mt * 16 + lg * 4 + r;
            float v = (acc[mt][nt][r] + bv[nt]) * cs;
            *(unsigned short*)(smem + lrow * 512 + ((col * 2) ^ ((lrow & 7) << 4))) = f2bf(v);
          }
      }
    }
    __syncthreads();
    #pragma unroll
    for (int it = 0; it < 4; ++it) {
      int c = it * 512 + tid;             // [0,2048): lrow 64 x cu 32
      int lrow = c >> 5, cu = c & 31;
      int4 val = *(const int4*)(smem + lrow * 512 + ((cu * 16) ^ ((lrow & 7) << 4)));
      int gtok = bm * 128 + hh * 64 + lrow;
      int w = gtok / 40, tk = gtok - w * 40;
      int h = cu >> 2;
      *(int4*)(base + (size_t)(w * 8 + h) * 2560 + tk * 64 + (cu & 3) * 16) = val;
    }
    __syncthreads();
  }
}

// ---- fused attention+proj v5: transposed bias + hoisted proj-B prefetch ----
// LDS 30720: BIAS [8 h][40 qi][80 B] @0 (25600, dead after logits) ;
//            P per-wave [48][80 B] x8 @0 (30720, after B2) ;
//            s_o [48][512 B] swz @0 (24576, after B3).
#define F3_LDS 30720

__global__ __launch_bounds__(512, 4)
void octa_attnproj3(const char* __restrict__ qg, const char* __restrict__ kg,
                    const char* __restrict__ vg, const float* __restrict__ maskp,
                    const int* __restrict__ rel_pos, const float* __restrict__ rpe_table,
                    const unsigned short* __restrict__ pTq, const float* __restrict__ proj_b,
                    float* __restrict__ out)
{
  extern __shared__ char smem[];
  const int tid = threadIdx.x, w = blockIdx.x, wid = tid >> 6;
  const int lane = tid & 63, ql = lane & 15, lg = lane >> 4, h = wid;
  const int perm = ql * 64 + lg * 16;
  const char* qb = qg + (size_t)(w * 8 + h) * 2560;
  const char* kb = kg + (size_t)(w * 8 + h) * 2560;
  const char* vb = vg + (size_t)(w * 8 + h) * 2560;
  const int c0 = wid * 32;
  const char* pB = (const char*)pTq;

  // fragment loads issued up-front (latency hides under bias phase)
  bf16x8 kf0 = ld16(kb + perm), kf1 = ld16(kb + 1024 + perm), kf2 = ld16(kb + 2048 + perm);
  bf16x8 qf0 = ld16(qb + perm), qf1 = ld16(qb + 1024 + perm), qf2 = ld16(qb + 2048 + perm);
  // vT fragments via scalar gather from the L2-hot 2.5KB v slice ([tok][d] rows)
  union U8 { unsigned short u[8]; bf16x8 v; };
  U8 ua, ub, uc, ud;
  #pragma unroll
  for (int j = 0; j < 8; ++j) {
    int tok = lg * 8 + j;
    ua.u[j] = *(const unsigned short*)(vb + tok * 64 + ql * 2);
    ub.u[j] = *(const unsigned short*)(vb + tok * 64 + (16 + ql) * 2);
  }
  if (lg == 0) {
    #pragma unroll
    for (int j = 0; j < 8; ++j) {
      uc.u[j] = *(const unsigned short*)(vb + (32 + j) * 64 + ql * 2);
      ud.u[j] = *(const unsigned short*)(vb + (32 + j) * 64 + (16 + ql) * 2);
    }
  } else {
    #pragma unroll
    for (int j = 0; j < 8; ++j) { uc.u[j] = 0; ud.u[j] = 0; }
  }
  bf16x8 vA = ua.v, vB = ub.v, vC = uc.v, vD = ud.v;

  // phase 0: cooperative bias -> BIAS[h][qi][kj] bf16 (80B rows; rpe from global)
  for (int e = tid; e < 1600; e += 512) {
    int qi = e / 40, kj = e - qi * 40;
    float m = maskp[(size_t)w * 1600 + e];
    float b8[8];
    if (qi >= 8 && kj >= 8) {
      const int* rp = rel_pos + ((size_t)w * 1024 + (qi - 8) * 32 + (kj - 8)) * 3;
      int c0_ = rp[0], c1 = rp[1], c2 = rp[2];
      c0_ = min(25, max(-25, c0_)); c1 = min(25, max(-25, c1)); c2 = min(25, max(-25, c2));
      const float4* r0 = (const float4*)(rpe_table + (c0_ + 25) * 8);
      const float4* r1 = (const float4*)(rpe_table + (c1 + 76) * 8);
      const float4* r2 = (const float4*)(rpe_table + (c2 + 127) * 8);
      float4 a0 = r0[0], a1 = r1[0], a2 = r2[0];
      float4 b0 = r0[1], b1 = r1[1], b2 = r2[1];
      b8[0] = m + a0.x + a1.x + a2.x; b8[1] = m + a0.y + a1.y + a2.y;
      b8[2] = m + a0.z + a1.z + a2.z; b8[3] = m + a0.w + a1.w + a2.w;
      b8[4] = m + b0.x + b1.x + b2.x; b8[5] = m + b0.y + b1.y + b2.y;
      b8[6] = m + b0.z + b1.z + b2.z; b8[7] = m + b0.w + b1.w + b2.w;
    } else {
      #pragma unroll
      for (int hh = 0; hh < 8; ++hh) b8[hh] = m;
    }
    #pragma unroll
    for (int hh = 0; hh < 8; ++hh)
      *(unsigned short*)(smem + hh * 3200 + qi * 80 + kj * 2) = f2bf(b8[hh]);
  }

  // QK^T (register-only): ST[kj][qi] = mfma(A=k, B=q)
  f32x4 st[9];
  {
    bf16x8 kf[3] = {kf0, kf1, kf2}, qf[3] = {qf0, qf1, qf2};
    __builtin_amdgcn_s_setprio(1);
    #pragma unroll
    for (int a = 0; a < 3; ++a)
      #pragma unroll
      for (int b = 0; b < 3; ++b)
        st[a * 3 + b] = __builtin_amdgcn_mfma_f32_16x16x32_bf16(
            kf[a], qf[b], (f32x4){0.f, 0.f, 0.f, 0.f}, 0, 0, 0);
    __builtin_amdgcn_s_setprio(0);
  }
  __syncthreads();   // B1: bias visible

  // logits: one 8B LDS read covers 4 consecutive kj (r=0..3)
  const char* bb_ = smem + h * 3200;
  float mx[3] = {-3e38f, -3e38f, -3e38f};
  #pragma unroll
  for (int a = 0; a < 3; ++a) {
    #pragma unroll
    for (int b = 0; b < 3; ++b) {
      int kj0 = a * 16 + lg * 4;
      int qi = b * 16 + ql;
      unsigned bx = 0, by = 0;
      if (kj0 < 40 && qi < 40) {
        uint2 t = *(const uint2*)(bb_ + qi * 80 + kj0 * 2);
        bx = t.x; by = t.y;
      }
      unsigned short bv4[4] = {
        (unsigned short)(bx & 0xFFFFu), (unsigned short)(bx >> 16),
        (unsigned short)(by & 0xFFFFu), (unsigned short)(by >> 16)
      };
      #pragma unroll
      for (int r = 0; r < 4; ++r) {
        int kj = kj0 + r;
        float s = st[a * 3 + b][r];
        if (kj < 40) {
          if (qi < 40) s += bf2f(bv4[r]);
        } else {
          s = -1e30f;
        }
        st[a * 3 + b][r] = s;
        mx[b] = fmaxf(mx[b], s);
      }
    }
  }
  __syncthreads();   // B2: bias reads done -> P region writable

  #pragma unroll
  for (int b = 0; b < 3; ++b) {
    mx[b] = fmaxf(mx[b], __shfl_xor(mx[b], 16));
    mx[b] = fmaxf(mx[b], __shfl_xor(mx[b], 32));
  }
  float sum[3] = {0.f, 0.f, 0.f};
  #pragma unroll
  for (int a = 0; a < 3; ++a)
    #pragma unroll
    for (int b = 0; b < 3; ++b)
      #pragma unroll
      for (int r = 0; r < 4; ++r) {
        float e = __expf(st[a * 3 + b][r] - mx[b]);
        st[a * 3 + b][r] = e;
        sum[b] += e;
      }
  float inv[3];
  #pragma unroll
  for (int b = 0; b < 3; ++b) {
    sum[b] += __shfl_xor(sum[b], 16);
    sum[b] += __shfl_xor(sum[b], 32);
    inv[b] = 1.f / sum[b];
  }

  // PV in two kj-halves; per-wave P buffer @ wid*3840, 80B rows
  char* pb_ = smem + wid * 3840;
  f32x4 ot[6];
  #pragma unroll
  for (int i = 0; i < 6; ++i) ot[i] = (f32x4){0.f, 0.f, 0.f, 0.f};

  #pragma unroll
  for (int a = 0; a < 2; ++a)
    #pragma unroll
    for (int b = 0; b < 3; ++b)
      #pragma unroll
      for (int r = 0; r < 4; ++r) {
        int kj = a * 16 + lg * 4 + r, qi = b * 16 + ql;
        *(unsigned short*)(pb_ + qi * 80 + kj * 2) = f2bf(st[a * 3 + b][r] * inv[b]);
      }
  asm volatile("" ::: "memory");
  __builtin_amdgcn_s_setprio(1);
  #pragma unroll
  for (int b = 0; b < 3; ++b) {
    bf16x8 pf = ld16(pb_ + (b * 16 + ql) * 80 + lg * 16);
    ot[b]     = __builtin_amdgcn_mfma_f32_16x16x32_bf16(vA, pf, ot[b], 0, 0, 0);
    ot[3 + b] = __builtin_amdgcn_mfma_f32_16x16x32_bf16(vB, pf, ot[3 + b], 0, 0, 0);
  }
  __builtin_amdgcn_s_setprio(0);
  asm volatile("" ::: "memory");
  #pragma unroll
  for (int b = 0; b < 3; ++b) {
    int qi = b * 16 + ql;
    #pragma unroll
    for (int r = 0; r < 4; ++r)
      *(unsigned short*)(pb_ + qi * 80 + (lg * 4 + r) * 2) = f2bf(st[6 + b][r] * inv[b]);
    *(uint2*)(pb_ + qi * 80 + 32 + lg * 8) = make_uint2(0u, 0u);
  }
  asm volatile("" ::: "memory");
  __builtin_amdgcn_s_setprio(1);
  #pragma unroll
  for (int b = 0; b < 3; ++b) {
    bf16x8 pf = ld16(pb_ + (b * 16 + ql) * 80 + lg * 16);
    ot[b]     = __builtin_amdgcn_mfma_f32_16x16x32_bf16(vC, pf, ot[b], 0, 0, 0);
    ot[3 + b] = __builtin_amdgcn_mfma_f32_16x16x32_bf16(vD, pf, ot[3 + b], 0, 0, 0);
  }
  __builtin_amdgcn_s_setprio(0);

  __syncthreads();   // B3: P dead (st dead too -> VGPRs free for prefetch)

  // hoisted proj-B prefetch: all 16 fragments issued now (pTq is L2-hot);
  // latency hides under s_o stores + B4 + af reads.
  bf16x8 bfrA[16];
  #pragma unroll
  for (int t = 0; t < 8; ++t)
    #pragma unroll
    for (int nt = 0; nt < 2; ++nt) {
      int n = c0 + nt * 16 + ql;
      bfrA[t * 2 + nt] =
          ld16(pB + (size_t)t * 16384 + n * 64 + ((lg * 16) ^ (((n >> 1) & 3) << 4)));
    }

  #pragma unroll
  for (int dm = 0; dm < 2; ++dm)
    #pragma unroll
    for (int b = 0; b < 3; ++b) {
      int qi = b * 16 + ql;
      unsigned u0 = pk2(ot[dm * 3 + b][0], ot[dm * 3 + b][1]);
      unsigned u1 = pk2(ot[dm * 3 + b][2], ot[dm * 3 + b][3]);
      int colb = (h * 32 + dm * 16 + lg * 4) * 2;
      *(uint2*)(smem + qi * 512 + (colb ^ ((qi & 7) << 4))) = make_uint2(u0, u1);
    }
  __syncthreads();   // B4: s_o visible

  f32x4 pacc[3][2];
  #pragma unroll
  for (int m = 0; m < 3; ++m)
    #pragma unroll
    for (int n = 0; n < 2; ++n) pacc[m][n] = (f32x4){0.f, 0.f, 0.f, 0.f};

  #pragma unroll
  for (int t = 0; t < 8; ++t) {
    bf16x8 af[3];
    #pragma unroll
    for (int mt = 0; mt < 3; ++mt) {
      int row = mt * 16 + ql;
      af[mt] = ld16(smem + row * 512 + ((t * 64 + lg * 16) ^ ((row & 7) << 4)));
    }
    __builtin_amdgcn_s_setprio(1);
    #pragma unroll
    for (int nt = 0; nt < 2; ++nt)
      #pragma unroll
      for (int mt = 0; mt < 3; ++mt)
        pacc[mt][nt] = __builtin_amdgcn_mfma_f32_16x16x32_bf16(af[mt], bfrA[t * 2 + nt], pacc[mt][nt], 0, 0, 0);
    __builtin_amdgcn_s_setprio(0);
  }

  #pragma unroll
  for (int nt = 0; nt < 2; ++nt) {
    int col = c0 + nt * 16 + ql;
    float pb = proj_b[col];
    #pragma unroll
    for (int mt = 0; mt < 3; ++mt)
      #pragma unroll
      for (int r = 0; r < 4; ++r) {
        int row = mt * 16 + lg * 4 + r;
        if (row < 40)
          out[(size_t)(w * 40 + row) * 256 + col] = pacc[mt][nt][r] + pb;
      }
  }
}

// ---- std finalize (all paths) ----
__global__ void octa_std(const float* __restrict__ ws, float* __restrict__ out,
                         int total_rows, size_t off)
{
  int j = blockIdx.x * 256 + threadIdx.x;
  if (j < 768) {
    float s = ws[j], ss = ws[768 + j];
    float T = (float)total_rows;
    float var = (ss - s * s / T) / (T - 1.f);
    out[off + j] = sqrtf(fmaxf(var, 0.f));
  }
}

// =======================================================================
// FALLBACK PATH: round-4 fused kernel (verified), used if ws too small
// =======================================================================
#define O_RPE 0
#define O_MSK 4896
#define O_IDX 8096
#define O_A   12192
#define O_ATT 36768
#define B1_SZ 49152
#define ATT_STRIDE 11776
#define AK 3840
#define AV 7680
#define B2_S (O_ATT + 94208)
#define B2_A O_ATT
#define LDS_BYTES_V4 163744

__device__ __forceinline__ int a_addr(int row, int byte) {
  return O_A + row * 512 + (byte ^ ((row & 7) << 4));
}
__device__ __forceinline__ int v_addr(int d, int byte) {
  return AV + d * 128 + (byte ^ ((d & 7) << 4));
}

__global__ void octa_prep_v4(const float* __restrict__ qkv_w, const float* __restrict__ proj_w,
                             unsigned short* __restrict__ wTq, unsigned short* __restrict__ pTq)
{
  int idx = blockIdx.x * 256 + threadIdx.x;
  if (idx < 196608) {
    int n = idx >> 8, k = idx & 255;
    wTq[idx] = f2bf(qkv_w[k * 768 + n]);
  } else {
    int i = idx - 196608;
    int n = i >> 8, k = i & 255;
    pTq[i] = f2bf(proj_w[k * 256 + n]);
  }
}

__global__ __launch_bounds__(512, 2)
void octa_main_v4(const float* __restrict__ data, const int* __restrict__ rel_pos,
                  const float* __restrict__ maskp, const float* __restrict__ qkv_b,
                  const float* __restrict__ proj_b, const float* __restrict__ rpe_table,
                  const unsigned short* __restrict__ wTq, const unsigned short* __restrict__ pTq,
                  float* __restrict__ ws, float* __restrict__ out)
{
  extern __shared__ char smem[];
  float* s_rpe = (float*)(smem + O_RPE);
  const int tid = threadIdx.x;
  const int w   = blockIdx.x;
  const int wid = tid >> 6;
  const int lane = tid & 63;
  const int ql = lane & 15;
  const int lg = lane >> 4;
  const int h  = wid;
  const int ab = O_ATT + wid * ATT_STRIDE;

  {
    #pragma unroll
    for (int it = 0; it < 6; ++it) {
      int g = it * 512 + tid;
      int n = g >> 2, slot = g & 3;
      const char* src = (const char*)wTq + (size_t)n * 512 + ((slot * 16) ^ ((n & 3) << 4));
      gll16(src, smem + O_ATT + it * 8192 + wid * 1024);
    }
  }
  for (int f = tid; f < 1224; f += 512) s_rpe[f] = rpe_table[f];
  for (int f = tid; f < 400; f += 512) {
    float4 m4 = ((const float4*)(maskp + (size_t)w * 1600))[f];
    uint2 pk;
    pk.x = pk2(m4.x, m4.y); pk.y = pk2(m4.z, m4.w);
    *(uint2*)(smem + O_MSK + f * 8) = pk;
  }
  for (int p = tid; p < 1024; p += 512) {
    const int* rp = rel_pos + ((size_t)w * 1024 + p) * 3;
    int c0 = rp[0], c1 = rp[1], c2 = rp[2];
    c0 = min(25, max(-25, c0)); c1 = min(25, max(-25, c1)); c2 = min(25, max(-25, c2));
    unsigned pk = (unsigned)(c0 + 25) | ((unsigned)(c1 + 76) << 10) | ((unsigned)(c2 + 127) << 20);
    *(unsigned*)(smem + O_IDX + ((p * 4) ^ (((p >> 5) & 7) << 4))) = pk;
  }
  {
    const float4* src = (const float4*)(data + (size_t)w * 10240);
    for (int f = tid; f < 2560; f += 512) {
      int token = f >> 6, q4 = f & 63;
      float4 d4 = src[f];
      uint2 pk;
      pk.x = pk2(d4.x, d4.y); pk.y = pk2(d4.z, d4.w);
      *(uint2*)(smem + a_addr(token, q4 * 8)) = pk;
    }
    int token = 40 + (tid >> 6), byte = (tid & 63) * 8;
    *(uint2*)(smem + a_addr(token, byte)) = make_uint2(0u, 0u);
  }
  __syncthreads();

  f32x4 acc[18];
  #pragma unroll
  for (int i = 0; i < 18; ++i) acc[i] = (f32x4){0.f, 0.f, 0.f, 0.f};

  for (int t = 0; t < 8; ++t) {
    if (t < 7) {
      int bb = O_ATT + ((t + 1) & 1) * B1_SZ;
      #pragma unroll
      for (int it = 0; it < 6; ++it) {
        int g = it * 512 + tid;
        int n = g >> 2, slot = g & 3;
        const char* src = (const char*)wTq + (size_t)n * 512 + (t + 1) * 64
                          + ((slot * 16) ^ ((n & 3) << 4));
        gll16(src, smem + bb + it * 8192 + wid * 1024);
      }
    }
    const int bb = O_ATT + (t & 1) * B1_SZ;
    bf16x8 af[3];
    #pragma unroll
    for (int mt = 0; mt < 3; ++mt)
      af[mt] = ld16(smem + a_addr(mt * 16 + ql, t * 64 + lg * 16));
    #pragma unroll
    for (int j = 0; j < 6; ++j) {
      int n = ((j >> 1) * 16 + 2 * wid + (j & 1)) * 16 + ql;
      bf16x8 bf = ld16(smem + bb + n * 64 + ((lg * 16) ^ ((n & 3) << 4)));
      #pragma unroll
      for (int mt = 0; mt < 3; ++mt)
        acc[j * 3 + mt] = __builtin_amdgcn_mfma_f32_16x16x32_bf16(af[mt], bf, acc[j * 3 + mt], 0, 0, 0);
    }
    __syncthreads();
  }

  {
    #pragma unroll
    for (int it = 0; it < 4; ++it) {
      int g = it * 512 + tid;
      int n = g >> 3, slot = g & 7;
      const char* src = (const char*)pTq + (size_t)n * 512 + ((slot * 16) ^ ((n & 7) << 4));
      gll16(src, smem + B2_S + it * 8192 + wid * 1024);
    }
  }

  #pragma unroll
  for (int j = 0; j < 6; ++j) {
    int sec = j >> 1;
    int ncol = sec * 256 + 32 * wid + (j & 1) * 16 + ql;
    int d = (j & 1) * 16 + ql;
    float bias = qkv_b[ncol];
    float s1 = 0.f, s2 = 0.f;
    #pragma unroll
    for (int mt = 0; mt < 3; ++mt) {
      #pragma unroll
      for (int r = 0; r < 4; ++r) {
        int token = mt * 16 + lg * 4 + r;
        float v = acc[j * 3 + mt][r] + bias;
        if (token < 40) { s1 += v; s2 += v * v; }
        if (sec == 0)
          *(unsigned short*)(smem + ab + token * 80 + d * 2) = f2bf(v * SCALE_F);
        else if (sec == 1)
          *(unsigned short*)(smem + ab + AK + token * 80 + d * 2) = f2bf(v);
        else
          *(unsigned short*)(smem + ab + v_addr(d, token * 2)) = f2bf(v);
      }
    }
    s1 += __shfl_xor(s1, 16); s1 += __shfl_xor(s1, 32);
    s2 += __shfl_xor(s2, 16); s2 += __shfl_xor(s2, 32);
    if (lg == 0) { atomicAdd(ws + ncol, s1); atomicAdd(ws + 768 + ncol, s2); }
  }
  {
    int zd = lane >> 1;
    int zb = 96 + (lane & 1) * 16;
    *(int4*)(smem + ab + v_addr(zd, zb)) = (int4){0, 0, 0, 0};
  }
  asm volatile("" ::: "memory");

  f32x4 st[9];
  {
    bf16x8 kf[3], qf[3];
    #pragma unroll
    for (int a = 0; a < 3; ++a) kf[a] = ld16(smem + ab + AK + (a * 16 + ql) * 80 + lg * 16);
    #pragma unroll
    for (int b = 0; b < 3; ++b) qf[b] = ld16(smem + ab + (b * 16 + ql) * 80 + lg * 16);
    #pragma unroll
    for (int a = 0; a < 3; ++a)
      #pragma unroll
      for (int b = 0; b < 3; ++b)
        st[a * 3 + b] = __builtin_amdgcn_mfma_f32_16x16x32_bf16(
            kf[a], qf[b], (f32x4){0.f, 0.f, 0.f, 0.f}, 0, 0, 0);
  }

  float mx[3] = {-3e38f, -3e38f, -3e38f};
  #pragma unroll
  for (int a = 0; a < 3; ++a) {
    #pragma unroll
    for (int b = 0; b < 3; ++b) {
      #pragma unroll
      for (int r = 0; r < 4; ++r) {
        int kj = a * 16 + lg * 4 + r;
        int qi = b * 16 + ql;
        float s = st[a * 3 + b][r];
        if (kj < 40) {
          if (qi < 40) {
            s += bf2f(*(const unsigned short*)(smem + O_MSK + (qi * 40 + kj) * 2));
            if (kj >= 8 && qi >= 8) {
              int p = (qi - 8) * 32 + (kj - 8);
              unsigned pk = *(const unsigned*)(smem + O_IDX + ((p * 4) ^ (((p >> 5) & 7) << 4)));
              s += s_rpe[(pk & 1023) * 8 + h] + s_rpe[((pk >> 10) & 1023) * 8 + h]
                 + s_rpe[(pk >> 20) * 8 + h];
            }
          }
        } else {
          s = -1e30f;
        }
        st[a * 3 + b][r] = s;
        mx[b] = fmaxf(mx[b], s);
      }
    }
  }
  #pragma unroll
  for (int b = 0; b < 3; ++b) {
    mx[b] = fmaxf(mx[b], __shfl_xor(mx[b], 16));
    mx[b] = fmaxf(mx[b], __shfl_xor(mx[b], 32));
  }
  float sum[3] = {0.f, 0.f, 0.f};
  #pragma unroll
  for (int a = 0; a < 3; ++a)
    #pragma unroll
    for (int b = 0; b < 3; ++b)
      #pragma unroll
      for (int r = 0; r < 4; ++r) {
        float e = __expf(st[a * 3 + b][r] - mx[b]);
        st[a * 3 + b][r] = e;
        sum[b] += e;
      }
  float inv[3];
  #pragma unroll
  for (int b = 0; b < 3; ++b) {
    sum[b] += __shfl_xor(sum[b], 16);
    sum[b] += __shfl_xor(sum[b], 32);
    inv[b] = 1.f / sum[b];
  }

  f32x4 ot[6];
  #pragma unroll
  for (int i = 0; i < 6; ++i) ot[i] = (f32x4){0.f, 0.f, 0.f, 0.f};

  #pragma unroll
  for (int a = 0; a < 2; ++a)
    #pragma unroll
    for (int b = 0; b < 3; ++b)
      #pragma unroll
      for (int r = 0; r < 4; ++r) {
        int kj = a * 16 + lg * 4 + r, qi = b * 16 + ql;
        *(unsigned short*)(smem + ab + qi * 80 + kj * 2) = f2bf(st[a * 3 + b][r] * inv[b]);
      }
  asm volatile("" ::: "memory");
  {
    bf16x8 vf0 = ld16(smem + ab + v_addr(ql, lg * 16));
    bf16x8 vf1 = ld16(smem + ab + v_addr(16 + ql, lg * 16));
    #pragma unroll
    for (int b = 0; b < 3; ++b) {
      bf16x8 pf = ld16(smem + ab + (b * 16 + ql) * 80 + lg * 16);
      ot[b] = __builtin_amdgcn_mfma_f32_16x16x32_bf16(vf0, pf, ot[b], 0, 0, 0);
      ot[3 + b] = __builtin_amdgcn_mfma_f32_16x16x32_bf16(vf1, pf, ot[3 + b], 0, 0, 0);
    }
  }
  asm volatile("" ::: "memory");
  #pragma unroll
  for (int b = 0; b < 3; ++b) {
    int qi = b * 16 + ql;
    #pragma unroll
    for (int r = 0; r < 4; ++r) {
      int kj = 32 + lg * 4 + r;
      *(unsigned short*)(smem + ab + qi * 80 + (kj - 32) * 2) = f2bf(st[6 + b][r] * inv[b]);
    }
    *(uint2*)(smem + ab + qi * 80 + 32 + lg * 8) = make_uint2(0u, 0u);
  }
  asm volatile("" ::: "memory");
  {
    bf16x8 vf0 = ld16(smem + ab + v_addr(ql, 64 + lg * 16));
    bf16x8 vf1 = ld16(smem + ab + v_addr(16 + ql, 64 + lg * 16));
    #pragma unroll
    for (int b = 0; b < 3; ++b) {
      bf16x8 pf = ld16(smem + ab + (b * 16 + ql) * 80 + lg * 16);
      ot[b] = __builtin_amdgcn_mfma_f32_16x16x32_bf16(vf0, pf, ot[b], 0, 0, 0);
      ot[3 + b] = __builtin_amdgcn_mfma_f32_16x16x32_bf16(vf1, pf, ot[3 + b], 0, 0, 0);
    }
  }
  #pragma unroll
  for (int dm = 0; dm < 2; ++dm)
    #pragma unroll
    for (int b = 0; b < 3; ++b)
      #pragma unroll
      for (int r = 0; r < 4; ++r) {
        int d = dm * 16 + lg * 4 + r;
        int qi = b * 16 + ql;
        *(unsigned short*)(smem + a_addr(qi, (h * 32 + d) * 2)) = f2bf(ot[dm * 3 + b][r]);
      }
  __syncthreads();

  f32x4 oacc[6];
  #pragma unroll
  for (int i = 0; i < 6; ++i) oacc[i] = (f32x4){0.f, 0.f, 0.f, 0.f};

  for (int t = 0; t < 4; ++t) {
    if (t < 3) {
      int bb = ((t + 1) & 1) ? B2_A : B2_S;
      #pragma unroll
      for (int it = 0; it < 4; ++it) {
        int g = it * 512 + tid;
        int n = g >> 3, slot = g & 7;
        const char* src = (const char*)pTq + (size_t)n * 512 + (t + 1) * 128
                          + ((slot * 16) ^ ((n & 7) << 4));
        gll16(src, smem + bb + it * 8192 + wid * 1024);
      }
    }
    const int bb = (t & 1) ? B2_A : B2_S;
    #pragma unroll
    for (int ks = 0; ks < 2; ++ks) {
      bf16x8 af[3];
      #pragma unroll
      for (int mt = 0; mt < 3; ++mt)
        af[mt] = ld16(smem + a_addr(mt * 16 + ql, t * 128 + ks * 64 + lg * 16));
      #pragma unroll
      for (int nt = 0; nt < 2; ++nt) {
        int n = (2 * wid + nt) * 16 + ql;
        bf16x8 bf = ld16(smem + bb + n * 128 + ((ks * 64 + lg * 16) ^ ((n & 7) << 4)));
        #pragma unroll
        for (int mt = 0; mt < 3; ++mt)
          oacc[nt * 3 + mt] = __builtin_amdgcn_mfma_f32_16x16x32_bf16(af[mt], bf, oacc[nt * 3 + mt], 0, 0, 0);
      }
    }
    __syncthreads();
  }

  #pragma unroll
  for (int nt = 0; nt < 2; ++nt) {
    int ncol = (2 * wid + nt) * 16 + ql;
    float pb = proj_b[ncol];
    #pragma unroll
    for (int mt = 0; mt < 3; ++mt)
      #pragma unroll
      for (int r = 0; r < 4; ++r) {
        int token = mt * 16 + lg * 4 + r;
        if (token < 40)
          out[(size_t)w * 10240 + token * 256 + ncol] = oacc[nt * 3 + mt][r] + pb;
      }
  }
}

// =======================================================================
extern "C" void kernel_launch(void* const* d_in, const int* in_sizes, int n_in,
                              void* d_out, int out_size, void* d_ws, size_t ws_size,
                              hipStream_t stream) {
  const float* data    = (const float*)d_in[0];
  const int*   rel_pos = (const int*)d_in[1];
  const float* maskp   = (const float*)d_in[2];
  const float* qkv_w   = (const float*)d_in[3];
  const float* qkv_b   = (const float*)d_in[4];
  const float* proj_w  = (const float*)d_in[5];
  const float* proj_b  = (const float*)d_in[6];
  const float* rpe_tab = (const float*)d_in[7];
  float* out = (float*)d_out;
  float* ws  = (float*)d_ws;

  const int nw = in_sizes[1] / 3072;           // 4096
  const int total_rows = nw * 40;
  const size_t std_off = (size_t)nw * 10240;
  const size_t SZ = 83886080ull;               // one q/k/v tensor, bf16
  const int nbm = nw * 40 / 128;               // 1280

  const size_t WS1 = 530432ull + 3ull * SZ + 4096ull;

  unsigned short* wTq = (unsigned short*)((char*)d_ws + 6144);
  unsigned short* pTq = (unsigned short*)((char*)d_ws + 399360);

  hipMemsetAsync(ws, 0, 6144, stream);

  if (ws_size >= WS1) {
    char* qg = (char*)d_ws + 530432;
    char* kg = qg + SZ;
    char* vg = kg + SZ;
    char* dbf = (char*)d_out;                  // 84 MB staging: dead after qkv,
                                               // overwritten by attnproj3's out-write
    (void)hipFuncSetAttribute((const void*)octa_attnproj3,
                              hipFuncAttributeMaxDynamicSharedMemorySize, F3_LDS);
    hipLaunchKernelGGL(octa_prep2, dim3(1024), dim3(256), 0, stream, qkv_w, proj_w, wTq, pTq);
    hipLaunchKernelGGL(octa_dprep, dim3(nbm * 16), dim3(256), 0, stream, data, dbf);
    hipLaunchKernelGGL(octa_qkv, dim3(nbm * 3), dim3(512), KQ_LDS, stream,
                       dbf, qkv_b, wTq, ws, qg, kg, vg);
    hipLaunchKernelGGL(octa_attnproj3, dim3(nw), dim3(512), F3_LDS, stream,
                       qg, kg, vg, maskp, rel_pos, rpe_tab, pTq, proj_b, out);
    hipLaunchKernelGGL(octa_std, dim3(3), dim3(256), 0, stream, ws, out, total_rows, std_off);
  } else {
    hipLaunchKernelGGL(octa_prep_v4, dim3(1024), dim3(256), 0, stream, qkv_w, proj_w, wTq, pTq);
    (void)hipFuncSetAttribute((const void*)octa_main_v4,
                              hipFuncAttributeMaxDynamicSharedMemorySize, LDS_BYTES_V4);
    hipLaunchKernelGGL(octa_main_v4, dim3(nw), dim3(512), LDS_BYTES_V4, stream,
                       data, rel_pos, maskp, qkv_b, proj_b, rpe_tab, wTq, pTq, ws, out);
    hipLaunchKernelGGL(octa_std, dim3(3), dim3(256), 0, stream, ws, out, total_rows, std_off);
  }
}